// Round 9
// baseline (1501.772 us; speedup 1.0000x reference)
//
#include <hip/hip_runtime.h>
#include <hip/hip_fp16.h>

// ---------------------------------------------------------------------------
// GIN (5 layers) + BN + graph pooling + MLP head.
// R9: one fused kernel per layer (gather + 2 matvecs + stats/pooling):
//     - phase A: per-wave CSR gather (8-deep ILP, s_load col) for 16 nodes,
//       BN affine folded, results written straight into the swizzled LDS
//       tile -> the agg/h16 HBM round-trip (~210 MB total) is deleted.
//     - phase B/C: identical to R8's k_mlp (scalar-pipe weights, fp16 out,
//       fp32 stats + pooling).
//     - tail: last block (ctr atomic + threadfence) computes next layer's
//       BN affine (a,b) -> 5 k_bnstat launches removed.
//     Ping-pong fp16 node buffers (fused kernel can't run in place).
//     27 -> 12 dispatches.
// ---------------------------------------------------------------------------

#define SCAN_ELEMS 1024

__device__ __forceinline__ unsigned short f2h(float f) {
    return __half_as_ushort(__float2half_rn(f));
}
__device__ __forceinline__ float h2f(unsigned short s) {
    return __half2float(__ushort_as_half(s));
}

// Edge histogram + rank (atomic returns slot) + node prep (x->fp16 pad, graph counts)
__global__ __launch_bounds__(256) void k_hist(const int* __restrict__ dst, int E,
        int* __restrict__ cnt_node, int* __restrict__ rank_,
        const int* __restrict__ batch, int N, int* __restrict__ cnt_graph,
        const float* __restrict__ x, unsigned short* __restrict__ x16h) {
    int i = blockIdx.x * blockDim.x + threadIdx.x;
    if (i < E) rank_[i] = atomicAdd(&cnt_node[dst[i]], 1);
    if (i < N) {
        atomicAdd(&cnt_graph[batch[i]], 1);
#pragma unroll
        for (int k = 0; k < 11; ++k) x16h[i * 16 + k] = f2h(x[i * 11 + k]);
#pragma unroll
        for (int k = 11; k < 16; ++k) x16h[i * 16 + k] = 0;
    }
}

__global__ __launch_bounds__(256) void k_scan1(const int* __restrict__ cnt, int n,
        int* __restrict__ rp, int* __restrict__ bsum) {
    __shared__ int sdata[256];
    int t = threadIdx.x;
    int base = blockIdx.x * SCAN_ELEMS + t * 4;
    int v0 = (base + 0 < n) ? cnt[base + 0] : 0;
    int v1 = (base + 1 < n) ? cnt[base + 1] : 0;
    int v2 = (base + 2 < n) ? cnt[base + 2] : 0;
    int v3 = (base + 3 < n) ? cnt[base + 3] : 0;
    int tsum = v0 + v1 + v2 + v3;
    sdata[t] = tsum;
    __syncthreads();
    for (int off = 1; off < 256; off <<= 1) {
        int val = (t >= off) ? sdata[t - off] : 0;
        __syncthreads();
        sdata[t] += val;
        __syncthreads();
    }
    int excl = sdata[t] - tsum;
    if (t == 255) bsum[blockIdx.x] = sdata[255];
    if (base + 0 < n) rp[base + 0] = excl;
    if (base + 1 < n) rp[base + 1] = excl + v0;
    if (base + 2 < n) rp[base + 2] = excl + v0 + v1;
    if (base + 3 < n) rp[base + 3] = excl + v0 + v1 + v2;
}

__global__ __launch_bounds__(128) void k_scan2(const int* __restrict__ bsum, int nb,
        int* __restrict__ boffs) {
    __shared__ int sd[128];
    int t = threadIdx.x;
    int v = (t < nb) ? bsum[t] : 0;
    sd[t] = v;
    __syncthreads();
    for (int off = 1; off < 128; off <<= 1) {
        int val = (t >= off) ? sd[t - off] : 0;
        __syncthreads();
        sd[t] += val;
        __syncthreads();
    }
    if (t < nb) boffs[t] = sd[t] - v;
}

__global__ __launch_bounds__(256) void k_scan3(int* __restrict__ rp, int n,
        const int* __restrict__ boffs, int E) {
    int i = blockIdx.x * blockDim.x + threadIdx.x;
    if (i < n) rp[i] += boffs[i / SCAN_ELEMS];
    if (i == 0) rp[n] = E;
}

__global__ __launch_bounds__(256) void k_fill(const int* __restrict__ src,
        const int* __restrict__ dst, const int* __restrict__ rank_, int E,
        const int* __restrict__ rp, int* __restrict__ col) {
    int e = blockIdx.x * blockDim.x + threadIdx.x;
    if (e < E) {
        __builtin_nontemporal_store(src[e], &col[rp[dst[e]] + rank_[e]]);
    }
}

// Fused GIN layer: one block = 64-node tile.
//  A) gather (fp16 neighbors) + BN affine -> swizzled LDS
//  B) two 64x64 (or 11x64) matvecs, weights via scalar pipe
//  C) fp16 store + BN partial stats + graph pooling
//  D) last block computes next-layer BN affine (a,b)
template <bool FIRST>
__global__ __launch_bounds__(256, 6) void k_layer(
        const unsigned short* __restrict__ vin,  // FIRST: x16h (Nx16) else vb (Nx64)
        unsigned short* __restrict__ vout,
        const int* __restrict__ rp, const int* __restrict__ col,
        const int* __restrict__ batch,
        const float* __restrict__ ab_prev,
        const float* __restrict__ Wa, const float* __restrict__ ba,
        const float* __restrict__ Wb, const float* __restrict__ bb,
        float* __restrict__ Sg, float* __restrict__ bnpart,
        int* __restrict__ ctr,
        const float* __restrict__ gamma, const float* __restrict__ beta,
        float* __restrict__ ab_out, int N) {
    __shared__ float hb[64 * 64];
    float4* hb4 = (float4*)hb;
    const int tid = threadIdx.x;
    const int lane = tid & 63;
    const int wv = tid >> 6;
    const int n0 = blockIdx.x * 64;
    const int l15 = lane & 15;
    const int c0 = __builtin_amdgcn_readfirstlane(wv) * 16;

    // ---- phase A: gather directly into LDS ----
    if (FIRST) {
        // 16-dim gather: 4 edges x 16 channels per iteration, transposed
        // into hs[k][node] (pitch 65, conflict-free)
        float* hs = hb;
        const int sub = lane >> 4, c = lane & 15;
        for (int t = 0; t < 16; ++t) {
            int nt = wv * 16 + t;
            int n = n0 + nt;
            float s0 = 0.f, s1 = 0.f;
            if (n < N) {
                int start = rp[n], end = rp[n + 1];
                int eb = start;
                for (; eb + 8 <= end; eb += 8) {
                    int j0 = col[eb + sub];
                    int j1 = col[eb + 4 + sub];
                    s0 += h2f(vin[(size_t)j0 * 16 + c]);
                    s1 += h2f(vin[(size_t)j1 * 16 + c]);
                }
                for (int e = eb + sub; e < end; e += 4)
                    s0 += h2f(vin[(size_t)col[e] * 16 + c]);
            }
            float s = s0 + s1;
            s += __shfl_xor(s, 16);
            s += __shfl_xor(s, 32);
            if (n < N && lane < 16)
                hs[lane * 65 + nt] = s + h2f(vin[(size_t)n * 16 + lane]);
        }
    } else {
        float a = ab_prev[lane];
        float b = ab_prev[64 + lane];
        for (int t = 0; t < 16; ++t) {
            int nt = wv * 16 + t;
            int n = n0 + nt;
            if (n < N) {
                int start = rp[n], end = rp[n + 1];
                float s0 = h2f(vin[(size_t)n * 64 + lane]);
                float s1 = 0.f, s2 = 0.f, s3 = 0.f, s4 = 0.f, s5 = 0.f, s6 = 0.f, s7 = 0.f;
                int e = start;
                for (; e + 8 <= end; e += 8) {
                    int j0 = col[e + 0], j1 = col[e + 1], j2 = col[e + 2], j3 = col[e + 3];
                    int j4 = col[e + 4], j5 = col[e + 5], j6 = col[e + 6], j7 = col[e + 7];
                    s0 += h2f(vin[(size_t)j0 * 64 + lane]);
                    s1 += h2f(vin[(size_t)j1 * 64 + lane]);
                    s2 += h2f(vin[(size_t)j2 * 64 + lane]);
                    s3 += h2f(vin[(size_t)j3 * 64 + lane]);
                    s4 += h2f(vin[(size_t)j4 * 64 + lane]);
                    s5 += h2f(vin[(size_t)j5 * 64 + lane]);
                    s6 += h2f(vin[(size_t)j6 * 64 + lane]);
                    s7 += h2f(vin[(size_t)j7 * 64 + lane]);
                }
                for (; e < end; ++e) s0 += h2f(vin[(size_t)col[e] * 64 + lane]);
                float s = ((s0 + s1) + (s2 + s3)) + ((s4 + s5) + (s6 + s7));
                float h2 = fmaf(a, s, b * (float)(1 + end - start));
                hb[nt * 64 + (((lane >> 2) ^ (nt & 15)) << 2) + (lane & 3)] = h2;
            }
        }
    }
    __syncthreads();

    float acc[16];

    // ---- phase B: matvec1 ----
    if (FIRST) {
        const float* hs = hb;
#pragma unroll
        for (int j = 0; j < 16; ++j) acc[j] = ba[c0 + j];
#pragma unroll
        for (int k = 0; k < 11; ++k) {
            float hk = hs[k * 65 + lane];
            const float* wr = Wa + k * 64 + c0;      // uniform -> s_load
#pragma unroll
            for (int j = 0; j < 16; ++j) acc[j] = fmaf(hk, wr[j], acc[j]);
        }
        __syncthreads();
#pragma unroll
        for (int j4 = 0; j4 < 4; ++j4) {
            int q = wv * 4 + j4;
            hb4[lane * 16 + (q ^ l15)] = make_float4(
                fmaxf(acc[j4 * 4 + 0], 0.f), fmaxf(acc[j4 * 4 + 1], 0.f),
                fmaxf(acc[j4 * 4 + 2], 0.f), fmaxf(acc[j4 * 4 + 3], 0.f));
        }
        __syncthreads();
    } else {
#pragma unroll
        for (int j = 0; j < 16; ++j) acc[j] = ba[c0 + j];
        for (int kc = 0; kc < 4; ++kc) {
            float hq[16];
#pragma unroll
            for (int q4 = 0; q4 < 4; ++q4) {
                float4 hv = hb4[lane * 16 + ((kc * 4 + q4) ^ l15)];
                hq[q4 * 4 + 0] = hv.x; hq[q4 * 4 + 1] = hv.y;
                hq[q4 * 4 + 2] = hv.z; hq[q4 * 4 + 3] = hv.w;
            }
            const float* wbase = Wa + (size_t)(kc * 16) * 64 + c0;   // uniform
#pragma unroll
            for (int kk = 0; kk < 16; ++kk) {
                float w[16];
#pragma unroll
                for (int j = 0; j < 16; ++j) w[j] = wbase[kk * 64 + j];  // s_load
                float hk = hq[kk];
#pragma unroll
                for (int j = 0; j < 16; ++j) acc[j] = fmaf(hk, w[j], acc[j]);
            }
        }
        __syncthreads();
#pragma unroll
        for (int j4 = 0; j4 < 4; ++j4) {
            int q = wv * 4 + j4;
            hb4[lane * 16 + (q ^ l15)] = make_float4(
                fmaxf(acc[j4 * 4 + 0], 0.f), fmaxf(acc[j4 * 4 + 1], 0.f),
                fmaxf(acc[j4 * 4 + 2], 0.f), fmaxf(acc[j4 * 4 + 3], 0.f));
        }
        __syncthreads();
    }

    // ---- matvec2 ----
#pragma unroll
    for (int j = 0; j < 16; ++j) acc[j] = bb[c0 + j];
    for (int kc = 0; kc < 4; ++kc) {
        float hq[16];
#pragma unroll
        for (int q4 = 0; q4 < 4; ++q4) {
            float4 hv = hb4[lane * 16 + ((kc * 4 + q4) ^ l15)];
            hq[q4 * 4 + 0] = hv.x; hq[q4 * 4 + 1] = hv.y;
            hq[q4 * 4 + 2] = hv.z; hq[q4 * 4 + 3] = hv.w;
        }
        const float* wbase = Wb + (size_t)(kc * 16) * 64 + c0;       // uniform
#pragma unroll
        for (int kk = 0; kk < 16; ++kk) {
            float w[16];
#pragma unroll
            for (int j = 0; j < 16; ++j) w[j] = wbase[kk * 64 + j];  // s_load
            float hk = hq[kk];
#pragma unroll
            for (int j = 0; j < 16; ++j) acc[j] = fmaf(hk, w[j], acc[j]);
        }
    }
    __syncthreads();
    {
#pragma unroll
        for (int j4 = 0; j4 < 4; ++j4) {
            int q = wv * 4 + j4;
            hb4[lane * 16 + (q ^ l15)] = make_float4(
                fmaxf(acc[j4 * 4 + 0], 0.f), fmaxf(acc[j4 * 4 + 1], 0.f),
                fmaxf(acc[j4 * 4 + 2], 0.f), fmaxf(acc[j4 * 4 + 3], 0.f));
        }
    }
    __syncthreads();

    // ---- phase C: fp16 store + BN stats + graph pooling (fp32) ----
    {
        int q = lane & 15;          // channel quad
        int ng = lane >> 4;         // node subgroup
        int base_nt = wv * 16;
        float4 bs = make_float4(0, 0, 0, 0), bq = make_float4(0, 0, 0, 0);

        bool full = (n0 + base_nt + 15) < N;            // wave-uniform
        int gf = 0, gl = -1;
        if (full) { gf = batch[n0 + base_nt]; gl = batch[n0 + base_nt + 15]; }

        if (full && gf == gl) {
            float4 pacc = make_float4(0, 0, 0, 0);
#pragma unroll
            for (int s2 = 0; s2 < 4; ++s2) {
                int nt = base_nt + s2 * 4 + ng;
                float4 v = hb4[nt * 16 + (q ^ (nt & 15))];
                ushort4 o;
                o.x = f2h(v.x); o.y = f2h(v.y); o.z = f2h(v.z); o.w = f2h(v.w);
                *(ushort4*)(vout + (size_t)(n0 + nt) * 64 + q * 4) = o;
                bs.x += v.x; bs.y += v.y; bs.z += v.z; bs.w += v.w;
                bq.x += v.x * v.x; bq.y += v.y * v.y;
                bq.z += v.z * v.z; bq.w += v.w * v.w;
                pacc.x += v.x; pacc.y += v.y; pacc.z += v.z; pacc.w += v.w;
            }
#pragma unroll
            for (int off = 16; off < 64; off <<= 1) {
                pacc.x += __shfl_xor(pacc.x, off); pacc.y += __shfl_xor(pacc.y, off);
                pacc.z += __shfl_xor(pacc.z, off); pacc.w += __shfl_xor(pacc.w, off);
            }
            if (ng == 0) {
                atomicAdd(&Sg[gf * 64 + q * 4 + 0], pacc.x);
                atomicAdd(&Sg[gf * 64 + q * 4 + 1], pacc.y);
                atomicAdd(&Sg[gf * 64 + q * 4 + 2], pacc.z);
                atomicAdd(&Sg[gf * 64 + q * 4 + 3], pacc.w);
            }
        } else {
            float4 pacc = make_float4(0, 0, 0, 0);
            int curg = -1;
#pragma unroll
            for (int s2 = 0; s2 < 4; ++s2) {
                int nt = base_nt + s2 * 4 + ng;
                int n = n0 + nt;
                if (n < N) {
                    float4 v = hb4[nt * 16 + (q ^ (nt & 15))];
                    ushort4 o;
                    o.x = f2h(v.x); o.y = f2h(v.y); o.z = f2h(v.z); o.w = f2h(v.w);
                    *(ushort4*)(vout + (size_t)n * 64 + q * 4) = o;
                    bs.x += v.x; bs.y += v.y; bs.z += v.z; bs.w += v.w;
                    bq.x += v.x * v.x; bq.y += v.y * v.y;
                    bq.z += v.z * v.z; bq.w += v.w * v.w;
                    int g = batch[n];
                    if (g != curg) {
                        if (curg >= 0) {
                            atomicAdd(&Sg[curg * 64 + q * 4 + 0], pacc.x);
                            atomicAdd(&Sg[curg * 64 + q * 4 + 1], pacc.y);
                            atomicAdd(&Sg[curg * 64 + q * 4 + 2], pacc.z);
                            atomicAdd(&Sg[curg * 64 + q * 4 + 3], pacc.w);
                        }
                        curg = g;
                        pacc = make_float4(0, 0, 0, 0);
                    }
                    pacc.x += v.x; pacc.y += v.y; pacc.z += v.z; pacc.w += v.w;
                }
            }
            if (curg >= 0) {
                atomicAdd(&Sg[curg * 64 + q * 4 + 0], pacc.x);
                atomicAdd(&Sg[curg * 64 + q * 4 + 1], pacc.y);
                atomicAdd(&Sg[curg * 64 + q * 4 + 2], pacc.z);
                atomicAdd(&Sg[curg * 64 + q * 4 + 3], pacc.w);
            }
        }
#pragma unroll
        for (int off = 16; off < 64; off <<= 1) {
            bs.x += __shfl_xor(bs.x, off); bs.y += __shfl_xor(bs.y, off);
            bs.z += __shfl_xor(bs.z, off); bs.w += __shfl_xor(bs.w, off);
            bq.x += __shfl_xor(bq.x, off); bq.y += __shfl_xor(bq.y, off);
            bq.z += __shfl_xor(bq.z, off); bq.w += __shfl_xor(bq.w, off);
        }
        if (ng == 0) {
            float* bkt = bnpart + (blockIdx.x & 31) * 128;
            atomicAdd(&bkt[q * 4 + 0], bs.x);
            atomicAdd(&bkt[q * 4 + 1], bs.y);
            atomicAdd(&bkt[q * 4 + 2], bs.z);
            atomicAdd(&bkt[q * 4 + 3], bs.w);
            atomicAdd(&bkt[64 + q * 4 + 0], bq.x);
            atomicAdd(&bkt[64 + q * 4 + 1], bq.y);
            atomicAdd(&bkt[64 + q * 4 + 2], bq.z);
            atomicAdd(&bkt[64 + q * 4 + 3], bq.w);
        }
    }

    // ---- phase D: last block computes next-layer BN affine ----
    __shared__ int is_last;
    __threadfence();
    if (tid == 0)
        is_last = (atomicAdd(ctr, 1) == (int)gridDim.x - 1) ? 1 : 0;
    __syncthreads();
    if (is_last && tid < 64) {
        float s = 0.f, q = 0.f;
        for (int i = 0; i < 32; ++i) {
            s += __hip_atomic_load(&bnpart[i * 128 + tid],
                                   __ATOMIC_RELAXED, __HIP_MEMORY_SCOPE_AGENT);
            q += __hip_atomic_load(&bnpart[i * 128 + 64 + tid],
                                   __ATOMIC_RELAXED, __HIP_MEMORY_SCOPE_AGENT);
        }
        float invN = 1.0f / (float)N;
        float mu = s * invN;
        float var = q * invN - mu * mu;
        float ac = gamma[tid] * rsqrtf(var + 1e-5f);
        ab_out[tid] = ac;
        ab_out[64 + tid] = beta[tid] - mu * ac;
    }
}

// Head: z[g,320] = concat_l (a_l*S_l[g] + b_l*cnt[g]); out = relu(z@fc1+b)@fc2+b
__global__ __launch_bounds__(256) void k_final(
        const float* __restrict__ S, const float* __restrict__ ab,
        const int* __restrict__ cntg,
        const float* __restrict__ fc1W, const float* __restrict__ fc1b,
        const float* __restrict__ fc2W, const float* __restrict__ fc2b,
        float* __restrict__ out, int G) {
    __shared__ float zbuf[4][320];
    int tid = threadIdx.x;
    int lane = tid & 63, wv = tid >> 6;
    int g = blockIdx.x * 4 + wv;
    if (g >= G) return;
    float cf = (float)cntg[g];
#pragma unroll
    for (int l = 0; l < 5; ++l) {
        float a = ab[l * 128 + lane];
        float b = ab[l * 128 + 64 + lane];
        zbuf[wv][l * 64 + lane] = a * S[((size_t)l * G + g) * 64 + lane] + b * cf;
    }
    float acc = fc1b[lane];
    for (int k = 0; k < 320; ++k) acc += zbuf[wv][k] * fc1W[k * 64 + lane];
    float t = fmaxf(acc, 0.f);
    float r = t * fc2W[lane];
#pragma unroll
    for (int off = 32; off >= 1; off >>= 1) r += __shfl_xor(r, off);
    if (lane == 0) out[g] = r + fc2b[0];
}

extern "C" void kernel_launch(void* const* d_in, const int* in_sizes, int n_in,
                              void* d_out, int out_size, void* d_ws, size_t ws_size,
                              hipStream_t stream) {
    const float* x    = (const float*)d_in[0];
    const int*   ei   = (const int*)d_in[1];
    const int*   batch= (const int*)d_in[2];
    const float* W1a  = (const float*)d_in[3];
    const float* b1a  = (const float*)d_in[4];
    const float* W1b  = (const float*)d_in[5];
    const float* b1b  = (const float*)d_in[6];
    const float* Wa   = (const float*)d_in[7];
    const float* ba   = (const float*)d_in[8];
    const float* Wb   = (const float*)d_in[9];
    const float* bb   = (const float*)d_in[10];
    const float* gamma= (const float*)d_in[11];
    const float* beta = (const float*)d_in[12];
    const float* fc1W = (const float*)d_in[13];
    const float* fc1b = (const float*)d_in[14];
    const float* fc2W = (const float*)d_in[15];
    const float* fc2b = (const float*)d_in[16];

    const int N = in_sizes[2];
    const int E = in_sizes[1] / 2;
    const int G = out_size;
    const int* srcp = ei;
    const int* dstp = ei + E;

    char* p = (char*)d_ws;
    auto alloc = [&](size_t bytes) {
        char* r = p;
        p += (bytes + 255) & ~size_t(255);
        return r;
    };
    unsigned short* vb0  = (unsigned short*)alloc((size_t)N * 64 * 2);
    unsigned short* vb1  = (unsigned short*)alloc((size_t)N * 64 * 2);
    int*   col    = (int*)  alloc((size_t)E * 4);
    int*   rank_  = (int*)  alloc((size_t)E * 4);
    int*   rp     = (int*)  alloc((size_t)(N + 1) * 4);
    unsigned short* x16h = (unsigned short*)alloc((size_t)N * 16 * 2);
    int*   bsum   = (int*)  alloc(512);
    int*   boffs  = (int*)  alloc(512);
    float* ab     = (float*)alloc(5 * 128 * 4);
    // ---- zeroed region (single memset) ----
    char*  z0     = p;
    int*   cntn   = (int*)  alloc((size_t)N * 4);
    int*   cntg   = (int*)  alloc((size_t)G * 4);
    float* S      = (float*)alloc((size_t)5 * G * 64 * 4);
    float* bnpart = (float*)alloc((size_t)5 * 32 * 128 * 4);
    int*   ctrs   = (int*)  alloc(5 * 4);
    size_t zbytes = (size_t)(p - z0);

    hipMemsetAsync(z0, 0, zbytes, stream);

    int nb_e = (E + 255) / 256;
    int nb_scan = (N + SCAN_ELEMS - 1) / SCAN_ELEMS;
    k_hist<<<nb_e, 256, 0, stream>>>(dstp, E, cntn, rank_, batch, N, cntg, x, x16h);
    k_scan1<<<nb_scan, 256, 0, stream>>>(cntn, N, rp, bsum);
    k_scan2<<<1, 128, 0, stream>>>(bsum, nb_scan, boffs);
    k_scan3<<<(N + 255) / 256, 256, 0, stream>>>(rp, N, boffs, E);
    k_fill<<<nb_e, 256, 0, stream>>>(srcp, dstp, rank_, E, rp, col);

    int nb_tile = (N + 63) / 64;

    // Layer 1 (fused): x16h -> vb0
    k_layer<true><<<nb_tile, 256, 0, stream>>>(x16h, vb0, rp, col, batch,
        nullptr, W1a, b1a, W1b, b1b,
        S, bnpart, ctrs, gamma, beta, ab, N);

    // Layers 2-5 (fused), ping-pong vb0/vb1
    unsigned short* vin = vb0;
    unsigned short* vout = vb1;
    for (int l = 0; l < 4; ++l) {
        k_layer<false><<<nb_tile, 256, 0, stream>>>(vin, vout, rp, col, batch,
            ab + l * 128,
            Wa + l * 4096, ba + l * 64, Wb + l * 4096, bb + l * 64,
            S + (size_t)(l + 1) * G * 64,
            bnpart + (size_t)(l + 1) * 32 * 128, ctrs + (l + 1),
            gamma + (l + 1) * 64, beta + (l + 1) * 64,
            ab + (l + 1) * 128, N);
        unsigned short* t = vout; vout = vin; vin = t;
    }

    k_final<<<(G + 3) / 4, 256, 0, stream>>>(S, ab, cntg, fc1W, fc1b, fc2W, fc2b,
                                             (float*)d_out, G);
}

// Round 10
// 1430.273 us; speedup vs baseline: 1.0500x; 1.0500x over previous
//
#include <hip/hip_runtime.h>
#include <hip/hip_fp16.h>

// ---------------------------------------------------------------------------
// GIN (5 layers) + BN + graph pooling + MLP head.
// R10: revert R9's layer fusion (split gather/mlp is ~3x faster: 100k tiny
//      independent waves hide L3 latency; fused tiles serialized 16 node-
//      gathers behind a block barrier at 42% occupancy). Keep from R9 only:
//      (a) bnstat folded into k_mlp tail block (ctr+threadfence), (b) k_prep
//      merged into k_hist. New: agg buffer stored fp16 (k_gather writes f2h,
//      k_mlp unpacks uint4->8ch) -> halves the 51 MB/layer round-trip.
//      27 -> 17 dispatches.
// ---------------------------------------------------------------------------

#define SCAN_ELEMS 1024

__device__ __forceinline__ unsigned short f2h(float f) {
    return __half_as_ushort(__float2half_rn(f));
}
__device__ __forceinline__ float h2f(unsigned short s) {
    return __half2float(__ushort_as_half(s));
}

// Edge histogram + rank + node prep (x->fp16 pad, graph counts)
__global__ __launch_bounds__(256) void k_hist(const int* __restrict__ dst, int E,
        int* __restrict__ cnt_node, int* __restrict__ rank_,
        const int* __restrict__ batch, int N, int* __restrict__ cnt_graph,
        const float* __restrict__ x, unsigned short* __restrict__ x16h) {
    int i = blockIdx.x * blockDim.x + threadIdx.x;
    if (i < E) rank_[i] = atomicAdd(&cnt_node[dst[i]], 1);
    if (i < N) {
        atomicAdd(&cnt_graph[batch[i]], 1);
#pragma unroll
        for (int k = 0; k < 11; ++k) x16h[i * 16 + k] = f2h(x[i * 11 + k]);
#pragma unroll
        for (int k = 11; k < 16; ++k) x16h[i * 16 + k] = 0;
    }
}

__global__ __launch_bounds__(256) void k_scan1(const int* __restrict__ cnt, int n,
        int* __restrict__ rp, int* __restrict__ bsum) {
    __shared__ int sdata[256];
    int t = threadIdx.x;
    int base = blockIdx.x * SCAN_ELEMS + t * 4;
    int v0 = (base + 0 < n) ? cnt[base + 0] : 0;
    int v1 = (base + 1 < n) ? cnt[base + 1] : 0;
    int v2 = (base + 2 < n) ? cnt[base + 2] : 0;
    int v3 = (base + 3 < n) ? cnt[base + 3] : 0;
    int tsum = v0 + v1 + v2 + v3;
    sdata[t] = tsum;
    __syncthreads();
    for (int off = 1; off < 256; off <<= 1) {
        int val = (t >= off) ? sdata[t - off] : 0;
        __syncthreads();
        sdata[t] += val;
        __syncthreads();
    }
    int excl = sdata[t] - tsum;
    if (t == 255) bsum[blockIdx.x] = sdata[255];
    if (base + 0 < n) rp[base + 0] = excl;
    if (base + 1 < n) rp[base + 1] = excl + v0;
    if (base + 2 < n) rp[base + 2] = excl + v0 + v1;
    if (base + 3 < n) rp[base + 3] = excl + v0 + v1 + v2;
}

__global__ __launch_bounds__(128) void k_scan2(const int* __restrict__ bsum, int nb,
        int* __restrict__ boffs) {
    __shared__ int sd[128];
    int t = threadIdx.x;
    int v = (t < nb) ? bsum[t] : 0;
    sd[t] = v;
    __syncthreads();
    for (int off = 1; off < 128; off <<= 1) {
        int val = (t >= off) ? sd[t - off] : 0;
        __syncthreads();
        sd[t] += val;
        __syncthreads();
    }
    if (t < nb) boffs[t] = sd[t] - v;
}

__global__ __launch_bounds__(256) void k_scan3(int* __restrict__ rp, int n,
        const int* __restrict__ boffs, int E) {
    int i = blockIdx.x * blockDim.x + threadIdx.x;
    if (i < n) rp[i] += boffs[i / SCAN_ELEMS];
    if (i == 0) rp[n] = E;
}

__global__ __launch_bounds__(256) void k_fill(const int* __restrict__ src,
        const int* __restrict__ dst, const int* __restrict__ rank_, int E,
        const int* __restrict__ rp, int* __restrict__ col) {
    int e = blockIdx.x * blockDim.x + threadIdx.x;
    if (e < E) {
        __builtin_nontemporal_store(src[e], &col[rp[dst[e]] + rank_[e]]);
    }
}

// Layer-1 gather in padded 11->16 dim fp16 space: wave = 1 node, 4 edges per
// iteration (16 lanes per edge), unroll 2 -> 8 edges in flight. fp32 out.
__global__ __launch_bounds__(256, 8) void k_gather16(
        const unsigned short* __restrict__ x16h, float* __restrict__ h16,
        const int* __restrict__ rp, const int* __restrict__ col, int N) {
    int lane = threadIdx.x & 63, wv = threadIdx.x >> 6;
    int n = blockIdx.x * 4 + wv;
    if (n >= N) return;
    int sub = lane >> 4, c = lane & 15;
    int start = rp[n], end = rp[n + 1];
    float s0 = 0.f, s1 = 0.f;
    int eb = start;
    for (; eb + 8 <= end; eb += 8) {
        int j0 = col[eb + sub];
        int j1 = col[eb + 4 + sub];
        s0 += h2f(x16h[(size_t)j0 * 16 + c]);
        s1 += h2f(x16h[(size_t)j1 * 16 + c]);
    }
    for (int e = eb + sub; e < end; e += 4) {
        s0 += h2f(x16h[(size_t)col[e] * 16 + c]);
    }
    float s = s0 + s1;
    s += __shfl_xor(s, 16);
    s += __shfl_xor(s, 32);
    if (lane < 16) {
        h16[(size_t)n * 16 + lane] = s + h2f(x16h[(size_t)n * 16 + lane]);
    }
}

// Gather (layers 2-5): one wave per node, lane = channel, fp16 in/out.
// s = v_n + sum_j v_j; h2 = a*s + b*(1+deg) in fp32; agg stored fp16.
__global__ __launch_bounds__(256, 8) void k_gather(
        const unsigned short* __restrict__ vin, unsigned short* __restrict__ aggh,
        const int* __restrict__ rp, const int* __restrict__ col,
        const float* __restrict__ ab_prev, int N) {
    int lane = threadIdx.x & 63, wv = threadIdx.x >> 6;
    int n = blockIdx.x * 4 + wv;
    if (n >= N) return;
    float a = ab_prev[lane];
    float b = ab_prev[64 + lane];
    int start = rp[n], end = rp[n + 1];
    float s0 = h2f(vin[(size_t)n * 64 + lane]);
    float s1 = 0.f, s2 = 0.f, s3 = 0.f, s4 = 0.f, s5 = 0.f, s6 = 0.f, s7 = 0.f;
    int e = start;
    for (; e + 8 <= end; e += 8) {
        int j0 = col[e + 0], j1 = col[e + 1], j2 = col[e + 2], j3 = col[e + 3];
        int j4 = col[e + 4], j5 = col[e + 5], j6 = col[e + 6], j7 = col[e + 7];
        s0 += h2f(vin[(size_t)j0 * 64 + lane]);
        s1 += h2f(vin[(size_t)j1 * 64 + lane]);
        s2 += h2f(vin[(size_t)j2 * 64 + lane]);
        s3 += h2f(vin[(size_t)j3 * 64 + lane]);
        s4 += h2f(vin[(size_t)j4 * 64 + lane]);
        s5 += h2f(vin[(size_t)j5 * 64 + lane]);
        s6 += h2f(vin[(size_t)j6 * 64 + lane]);
        s7 += h2f(vin[(size_t)j7 * 64 + lane]);
    }
    for (; e < end; ++e) s0 += h2f(vin[(size_t)col[e] * 64 + lane]);
    float s = ((s0 + s1) + (s2 + s3)) + ((s4 + s5) + (s6 + s7));
    float h2 = fmaf(a, s, b * (float)(1 + end - start));
    aggh[(size_t)n * 64 + lane] = f2h(h2);
}

// MLP: one block = one 64-node tile. k-chunked matvecs; weights via the
// scalar pipe. fp16 in (agg) / fp16 out (v). Tail block computes this
// layer's BN affine (a,b) for the next gather and k_final.
template <bool FIRST>
__global__ __launch_bounds__(256, 4) void k_mlp(
        const void* __restrict__ aggp, unsigned short* __restrict__ vout,
        const int* __restrict__ batch,
        const float* __restrict__ Wa, const float* __restrict__ ba,
        const float* __restrict__ Wb, const float* __restrict__ bb,
        float* __restrict__ Sg, float* __restrict__ bnpart,
        int* __restrict__ ctr,
        const float* __restrict__ gamma, const float* __restrict__ beta,
        float* __restrict__ ab_out, int N) {
    __shared__ float hb[64 * 64];
    float4* hb4 = (float4*)hb;
    const int tid = threadIdx.x;
    const int lane = tid & 63;
    const int wv = tid >> 6;
    const int n0 = blockIdx.x * 64;
    const int l15 = lane & 15;
    // wave-uniform channel base, provably uniform -> weight reads use s_load
    const int c0 = __builtin_amdgcn_readfirstlane(wv) * 16;

    float acc[16];

    if (FIRST) {
        // ---- phase A': h16 (fp32 Nx16) -> transposed LDS hs[k][node] ----
        const float* h16 = (const float*)aggp;
        float* hs = hb;
        {
            int n = tid >> 2, kq = tid & 3;
            float4 v = make_float4(0.f, 0.f, 0.f, 0.f);
            if (n0 + n < N) v = ((const float4*)h16)[(size_t)n0 * 4 + tid];
            hs[(kq * 4 + 0) * 64 + n] = v.x;
            hs[(kq * 4 + 1) * 64 + n] = v.y;
            hs[(kq * 4 + 2) * 64 + n] = v.z;
            hs[(kq * 4 + 3) * 64 + n] = v.w;
        }
        __syncthreads();
        // ---- matvec1: t[c0+j] = relu(sum_{k<11} h[k]*W1a[k][c0+j] + ba) ----
#pragma unroll
        for (int j = 0; j < 16; ++j) acc[j] = ba[c0 + j];
#pragma unroll
        for (int k = 0; k < 11; ++k) {
            float hk = hs[k * 64 + lane];            // conflict-free
            const float* wr = Wa + k * 64 + c0;      // uniform -> s_load
#pragma unroll
            for (int j = 0; j < 16; ++j) acc[j] = fmaf(hk, wr[j], acc[j]);
        }
        __syncthreads();   // done reading hs; safe to overwrite hb
#pragma unroll
        for (int j4 = 0; j4 < 4; ++j4) {
            int q = wv * 4 + j4;
            hb4[lane * 16 + (q ^ l15)] = make_float4(
                fmaxf(acc[j4 * 4 + 0], 0.f), fmaxf(acc[j4 * 4 + 1], 0.f),
                fmaxf(acc[j4 * 4 + 2], 0.f), fmaxf(acc[j4 * 4 + 3], 0.f));
        }
        __syncthreads();
    } else {
        // ---- phase A: fp16 tile (uint4 = 8ch) -> LDS (swizzled fp32) ----
        {
            const unsigned short* aggh = (const unsigned short*)aggp;
            const uint4* a4 = (const uint4*)(aggh + (size_t)n0 * 64);
#pragma unroll
            for (int r = 0; r < 2; ++r) {
                int i = tid + r * 256;          // ushort8 index within tile
                int nt = i >> 3, q8 = i & 7;
                uint4 u = make_uint4(0, 0, 0, 0);
                if (n0 + nt < N) u = a4[i];
                float4 v0, v1;
                v0.x = h2f((unsigned short)(u.x & 0xffff));
                v0.y = h2f((unsigned short)(u.x >> 16));
                v0.z = h2f((unsigned short)(u.y & 0xffff));
                v0.w = h2f((unsigned short)(u.y >> 16));
                v1.x = h2f((unsigned short)(u.z & 0xffff));
                v1.y = h2f((unsigned short)(u.z >> 16));
                v1.z = h2f((unsigned short)(u.w & 0xffff));
                v1.w = h2f((unsigned short)(u.w >> 16));
                int sw = nt & 15;
                hb4[nt * 16 + ((2 * q8 + 0) ^ sw)] = v0;
                hb4[nt * 16 + ((2 * q8 + 1) ^ sw)] = v1;
            }
        }
        __syncthreads();
        // ---- matvec1: t[c0+j] = relu(sum_k h[k]*Wa[k][c0+j] + ba[c0+j]) ----
#pragma unroll
        for (int j = 0; j < 16; ++j) acc[j] = ba[c0 + j];
        for (int kc = 0; kc < 4; ++kc) {
            float hq[16];
#pragma unroll
            for (int q4 = 0; q4 < 4; ++q4) {
                float4 hv = hb4[lane * 16 + ((kc * 4 + q4) ^ l15)];
                hq[q4 * 4 + 0] = hv.x; hq[q4 * 4 + 1] = hv.y;
                hq[q4 * 4 + 2] = hv.z; hq[q4 * 4 + 3] = hv.w;
            }
            const float* wbase = Wa + (size_t)(kc * 16) * 64 + c0;   // uniform
#pragma unroll
            for (int kk = 0; kk < 16; ++kk) {
                float w[16];
#pragma unroll
                for (int j = 0; j < 16; ++j) w[j] = wbase[kk * 64 + j];  // s_load
                float hk = hq[kk];
#pragma unroll
                for (int j = 0; j < 16; ++j) acc[j] = fmaf(hk, w[j], acc[j]);
            }
        }
        __syncthreads();   // everyone done reading h from hb
#pragma unroll
        for (int j4 = 0; j4 < 4; ++j4) {
            int q = wv * 4 + j4;
            hb4[lane * 16 + (q ^ l15)] = make_float4(
                fmaxf(acc[j4 * 4 + 0], 0.f), fmaxf(acc[j4 * 4 + 1], 0.f),
                fmaxf(acc[j4 * 4 + 2], 0.f), fmaxf(acc[j4 * 4 + 3], 0.f));
        }
        __syncthreads();
    }

    // ---- matvec2: v[c0+j] = relu(sum_k t[k]*Wb[k][c0+j] + bb[c0+j]) ----
#pragma unroll
    for (int j = 0; j < 16; ++j) acc[j] = bb[c0 + j];
    for (int kc = 0; kc < 4; ++kc) {
        float hq[16];
#pragma unroll
        for (int q4 = 0; q4 < 4; ++q4) {
            float4 hv = hb4[lane * 16 + ((kc * 4 + q4) ^ l15)];
            hq[q4 * 4 + 0] = hv.x; hq[q4 * 4 + 1] = hv.y;
            hq[q4 * 4 + 2] = hv.z; hq[q4 * 4 + 3] = hv.w;
        }
        const float* wbase = Wb + (size_t)(kc * 16) * 64 + c0;       // uniform
#pragma unroll
        for (int kk = 0; kk < 16; ++kk) {
            float w[16];
#pragma unroll
            for (int j = 0; j < 16; ++j) w[j] = wbase[kk * 64 + j];  // s_load
            float hk = hq[kk];
#pragma unroll
            for (int j = 0; j < 16; ++j) acc[j] = fmaf(hk, w[j], acc[j]);
        }
    }
    __syncthreads();   // everyone done reading hb
    {
#pragma unroll
        for (int j4 = 0; j4 < 4; ++j4) {
            int q = wv * 4 + j4;
            hb4[lane * 16 + (q ^ l15)] = make_float4(
                fmaxf(acc[j4 * 4 + 0], 0.f), fmaxf(acc[j4 * 4 + 1], 0.f),
                fmaxf(acc[j4 * 4 + 2], 0.f), fmaxf(acc[j4 * 4 + 3], 0.f));
        }
    }
    __syncthreads();

    // ---- phase C: fp16 store + BN stats + graph pooling (fp32) ----
    {
        int q = lane & 15;          // channel quad
        int ng = lane >> 4;         // node subgroup
        int base_nt = wv * 16;
        float4 bs = make_float4(0, 0, 0, 0), bq = make_float4(0, 0, 0, 0);

        bool full = (n0 + base_nt + 15) < N;            // wave-uniform
        int gf = 0, gl = -1;
        if (full) { gf = batch[n0 + base_nt]; gl = batch[n0 + base_nt + 15]; }

        if (full && gf == gl) {
            // fast path: whole 16-node group in one graph
            float4 pacc = make_float4(0, 0, 0, 0);
#pragma unroll
            for (int s2 = 0; s2 < 4; ++s2) {
                int nt = base_nt + s2 * 4 + ng;
                float4 v = hb4[nt * 16 + (q ^ (nt & 15))];
                ushort4 o;
                o.x = f2h(v.x); o.y = f2h(v.y); o.z = f2h(v.z); o.w = f2h(v.w);
                *(ushort4*)(vout + (size_t)(n0 + nt) * 64 + q * 4) = o;
                bs.x += v.x; bs.y += v.y; bs.z += v.z; bs.w += v.w;
                bq.x += v.x * v.x; bq.y += v.y * v.y;
                bq.z += v.z * v.z; bq.w += v.w * v.w;
                pacc.x += v.x; pacc.y += v.y; pacc.z += v.z; pacc.w += v.w;
            }
#pragma unroll
            for (int off = 16; off < 64; off <<= 1) {
                pacc.x += __shfl_xor(pacc.x, off); pacc.y += __shfl_xor(pacc.y, off);
                pacc.z += __shfl_xor(pacc.z, off); pacc.w += __shfl_xor(pacc.w, off);
            }
            if (ng == 0) {
                atomicAdd(&Sg[gf * 64 + q * 4 + 0], pacc.x);
                atomicAdd(&Sg[gf * 64 + q * 4 + 1], pacc.y);
                atomicAdd(&Sg[gf * 64 + q * 4 + 2], pacc.z);
                atomicAdd(&Sg[gf * 64 + q * 4 + 3], pacc.w);
            }
        } else {
            // slow path: graph boundary inside the group (or tile tail)
            float4 pacc = make_float4(0, 0, 0, 0);
            int curg = -1;
#pragma unroll
            for (int s2 = 0; s2 < 4; ++s2) {
                int nt = base_nt + s2 * 4 + ng;
                int n = n0 + nt;
                if (n < N) {
                    float4 v = hb4[nt * 16 + (q ^ (nt & 15))];
                    ushort4 o;
                    o.x = f2h(v.x); o.y = f2h(v.y); o.z = f2h(v.z); o.w = f2h(v.w);
                    *(ushort4*)(vout + (size_t)n * 64 + q * 4) = o;
                    bs.x += v.x; bs.y += v.y; bs.z += v.z; bs.w += v.w;
                    bq.x += v.x * v.x; bq.y += v.y * v.y;
                    bq.z += v.z * v.z; bq.w += v.w * v.w;
                    int g = batch[n];
                    if (g != curg) {
                        if (curg >= 0) {
                            atomicAdd(&Sg[curg * 64 + q * 4 + 0], pacc.x);
                            atomicAdd(&Sg[curg * 64 + q * 4 + 1], pacc.y);
                            atomicAdd(&Sg[curg * 64 + q * 4 + 2], pacc.z);
                            atomicAdd(&Sg[curg * 64 + q * 4 + 3], pacc.w);
                        }
                        curg = g;
                        pacc = make_float4(0, 0, 0, 0);
                    }
                    pacc.x += v.x; pacc.y += v.y; pacc.z += v.z; pacc.w += v.w;
                }
            }
            if (curg >= 0) {
                atomicAdd(&Sg[curg * 64 + q * 4 + 0], pacc.x);
                atomicAdd(&Sg[curg * 64 + q * 4 + 1], pacc.y);
                atomicAdd(&Sg[curg * 64 + q * 4 + 2], pacc.z);
                atomicAdd(&Sg[curg * 64 + q * 4 + 3], pacc.w);
            }
        }
#pragma unroll
        for (int off = 16; off < 64; off <<= 1) {
            bs.x += __shfl_xor(bs.x, off); bs.y += __shfl_xor(bs.y, off);
            bs.z += __shfl_xor(bs.z, off); bs.w += __shfl_xor(bs.w, off);
            bq.x += __shfl_xor(bq.x, off); bq.y += __shfl_xor(bq.y, off);
            bq.z += __shfl_xor(bq.z, off); bq.w += __shfl_xor(bq.w, off);
        }
        if (ng == 0) {
            float* bkt = bnpart + (blockIdx.x & 31) * 128;
            atomicAdd(&bkt[q * 4 + 0], bs.x);
            atomicAdd(&bkt[q * 4 + 1], bs.y);
            atomicAdd(&bkt[q * 4 + 2], bs.z);
            atomicAdd(&bkt[q * 4 + 3], bs.w);
            atomicAdd(&bkt[64 + q * 4 + 0], bq.x);
            atomicAdd(&bkt[64 + q * 4 + 1], bq.y);
            atomicAdd(&bkt[64 + q * 4 + 2], bq.z);
            atomicAdd(&bkt[64 + q * 4 + 3], bq.w);
        }
    }

    // ---- tail: last block computes this layer's BN affine (a,b) ----
    __shared__ int is_last;
    __threadfence();
    if (tid == 0)
        is_last = (atomicAdd(ctr, 1) == (int)gridDim.x - 1) ? 1 : 0;
    __syncthreads();
    if (is_last && tid < 64) {
        float s = 0.f, q = 0.f;
        for (int i = 0; i < 32; ++i) {
            s += __hip_atomic_load(&bnpart[i * 128 + tid],
                                   __ATOMIC_RELAXED, __HIP_MEMORY_SCOPE_AGENT);
            q += __hip_atomic_load(&bnpart[i * 128 + 64 + tid],
                                   __ATOMIC_RELAXED, __HIP_MEMORY_SCOPE_AGENT);
        }
        float invN = 1.0f / (float)N;
        float mu = s * invN;
        float var = q * invN - mu * mu;
        float ac = gamma[tid] * rsqrtf(var + 1e-5f);
        ab_out[tid] = ac;
        ab_out[64 + tid] = beta[tid] - mu * ac;
    }
}

// Head: z[g,320] = concat_l (a_l*S_l[g] + b_l*cnt[g]); out = relu(z@fc1+b)@fc2+b
__global__ __launch_bounds__(256) void k_final(
        const float* __restrict__ S, const float* __restrict__ ab,
        const int* __restrict__ cntg,
        const float* __restrict__ fc1W, const float* __restrict__ fc1b,
        const float* __restrict__ fc2W, const float* __restrict__ fc2b,
        float* __restrict__ out, int G) {
    __shared__ float zbuf[4][320];
    int tid = threadIdx.x;
    int lane = tid & 63, wv = tid >> 6;
    int g = blockIdx.x * 4 + wv;
    if (g >= G) return;
    float cf = (float)cntg[g];
#pragma unroll
    for (int l = 0; l < 5; ++l) {
        float a = ab[l * 128 + lane];
        float b = ab[l * 128 + 64 + lane];
        zbuf[wv][l * 64 + lane] = a * S[((size_t)l * G + g) * 64 + lane] + b * cf;
    }
    float acc = fc1b[lane];
    for (int k = 0; k < 320; ++k) acc += zbuf[wv][k] * fc1W[k * 64 + lane];
    float t = fmaxf(acc, 0.f);
    float r = t * fc2W[lane];
#pragma unroll
    for (int off = 32; off >= 1; off >>= 1) r += __shfl_xor(r, off);
    if (lane == 0) out[g] = r + fc2b[0];
}

extern "C" void kernel_launch(void* const* d_in, const int* in_sizes, int n_in,
                              void* d_out, int out_size, void* d_ws, size_t ws_size,
                              hipStream_t stream) {
    const float* x    = (const float*)d_in[0];
    const int*   ei   = (const int*)d_in[1];
    const int*   batch= (const int*)d_in[2];
    const float* W1a  = (const float*)d_in[3];
    const float* b1a  = (const float*)d_in[4];
    const float* W1b  = (const float*)d_in[5];
    const float* b1b  = (const float*)d_in[6];
    const float* Wa   = (const float*)d_in[7];
    const float* ba   = (const float*)d_in[8];
    const float* Wb   = (const float*)d_in[9];
    const float* bb   = (const float*)d_in[10];
    const float* gamma= (const float*)d_in[11];
    const float* beta = (const float*)d_in[12];
    const float* fc1W = (const float*)d_in[13];
    const float* fc1b = (const float*)d_in[14];
    const float* fc2W = (const float*)d_in[15];
    const float* fc2b = (const float*)d_in[16];

    const int N = in_sizes[2];
    const int E = in_sizes[1] / 2;
    const int G = out_size;
    const int* srcp = ei;
    const int* dstp = ei + E;

    char* p = (char*)d_ws;
    auto alloc = [&](size_t bytes) {
        char* r = p;
        p += (bytes + 255) & ~size_t(255);
        return r;
    };
    unsigned short* aggh = (unsigned short*)alloc((size_t)N * 64 * 2);
    unsigned short* vb   = (unsigned short*)alloc((size_t)N * 64 * 2);
    int*   col    = (int*)  alloc((size_t)E * 4);
    int*   rank_  = (int*)  alloc((size_t)E * 4);
    int*   rp     = (int*)  alloc((size_t)(N + 1) * 4);
    unsigned short* x16h = (unsigned short*)alloc((size_t)N * 16 * 2);
    float* h16    = (float*)alloc((size_t)N * 16 * 4);
    int*   bsum   = (int*)  alloc(512);
    int*   boffs  = (int*)  alloc(512);
    float* ab     = (float*)alloc(5 * 128 * 4);
    // ---- zeroed region (single memset) ----
    char*  z0     = p;
    int*   cntn   = (int*)  alloc((size_t)N * 4);
    int*   cntg   = (int*)  alloc((size_t)G * 4);
    float* S      = (float*)alloc((size_t)5 * G * 64 * 4);
    float* bnpart = (float*)alloc((size_t)5 * 32 * 128 * 4);
    int*   ctrs   = (int*)  alloc(5 * 4);
    size_t zbytes = (size_t)(p - z0);

    hipMemsetAsync(z0, 0, zbytes, stream);

    int nb_e = (E + 255) / 256;
    int nb_scan = (N + SCAN_ELEMS - 1) / SCAN_ELEMS;
    k_hist<<<nb_e, 256, 0, stream>>>(dstp, E, cntn, rank_, batch, N, cntg, x, x16h);
    k_scan1<<<nb_scan, 256, 0, stream>>>(cntn, N, rp, bsum);
    k_scan2<<<1, 128, 0, stream>>>(bsum, nb_scan, boffs);
    k_scan3<<<(N + 255) / 256, 256, 0, stream>>>(rp, N, boffs, E);
    k_fill<<<nb_e, 256, 0, stream>>>(srcp, dstp, rank_, E, rp, col);

    int nb_node = (N + 3) / 4;
    int nb_tile = (N + 63) / 64;

    // Layer 1: 16-dim fp16 gather, then mlp<FIRST> does W1a from h16 (fp32)
    k_gather16<<<nb_node, 256, 0, stream>>>(x16h, h16, rp, col, N);
    k_mlp<true><<<nb_tile, 256, 0, stream>>>(h16, vb, batch,
        W1a, b1a, W1b, b1b, S, bnpart, ctrs, gamma, beta, ab, N);

    for (int l = 0; l < 4; ++l) {
        k_gather<<<nb_node, 256, 0, stream>>>(vb, aggh, rp, col,
            ab + l * 128, N);
        k_mlp<false><<<nb_tile, 256, 0, stream>>>(aggh, vb, batch,
            Wa + l * 4096, ba + l * 64, Wb + l * 4096, bb + l * 64,
            S + (size_t)(l + 1) * G * 64,
            bnpart + (size_t)(l + 1) * 32 * 128, ctrs + (l + 1),
            gamma + (l + 1) * 64, beta + (l + 1) * 64,
            ab + (l + 1) * 128, N);
    }

    k_final<<<(G + 3) / 4, 256, 0, stream>>>(S, ab, cntg, fc1W, fc1b, fc2W, fc2b,
                                             (float*)d_out, G);
}

// Round 11
// 797.353 us; speedup vs baseline: 1.8834x; 1.7938x over previous
//
#include <hip/hip_runtime.h>
#include <hip/hip_fp16.h>

// ---------------------------------------------------------------------------
// GIN (5 layers) + BN + graph pooling + MLP head.
// R11: revert R10's per-block threadfence+ctr bnstat tail (device-scope fence
//      on 8 non-coherent XCD L2s => per-block L2 writeback, +150us/dispatch;
//      same defect explains R9's fused-kernel regression). Back to R8's
//      separate k_bnstat kernels. Kept from R10 (verified harmless/wins):
//      k_prep merged into k_hist, fp16 agg buffer (FETCH 13->6.9 MB),
//      non-temporal k_fill store.
// ---------------------------------------------------------------------------

#define SCAN_ELEMS 1024

__device__ __forceinline__ unsigned short f2h(float f) {
    return __half_as_ushort(__float2half_rn(f));
}
__device__ __forceinline__ float h2f(unsigned short s) {
    return __half2float(__ushort_as_half(s));
}

// Edge histogram + rank + node prep (x->fp16 pad, graph counts)
__global__ __launch_bounds__(256) void k_hist(const int* __restrict__ dst, int E,
        int* __restrict__ cnt_node, int* __restrict__ rank_,
        const int* __restrict__ batch, int N, int* __restrict__ cnt_graph,
        const float* __restrict__ x, unsigned short* __restrict__ x16h) {
    int i = blockIdx.x * blockDim.x + threadIdx.x;
    if (i < E) rank_[i] = atomicAdd(&cnt_node[dst[i]], 1);
    if (i < N) {
        atomicAdd(&cnt_graph[batch[i]], 1);
#pragma unroll
        for (int k = 0; k < 11; ++k) x16h[i * 16 + k] = f2h(x[i * 11 + k]);
#pragma unroll
        for (int k = 11; k < 16; ++k) x16h[i * 16 + k] = 0;
    }
}

__global__ __launch_bounds__(256) void k_scan1(const int* __restrict__ cnt, int n,
        int* __restrict__ rp, int* __restrict__ bsum) {
    __shared__ int sdata[256];
    int t = threadIdx.x;
    int base = blockIdx.x * SCAN_ELEMS + t * 4;
    int v0 = (base + 0 < n) ? cnt[base + 0] : 0;
    int v1 = (base + 1 < n) ? cnt[base + 1] : 0;
    int v2 = (base + 2 < n) ? cnt[base + 2] : 0;
    int v3 = (base + 3 < n) ? cnt[base + 3] : 0;
    int tsum = v0 + v1 + v2 + v3;
    sdata[t] = tsum;
    __syncthreads();
    for (int off = 1; off < 256; off <<= 1) {
        int val = (t >= off) ? sdata[t - off] : 0;
        __syncthreads();
        sdata[t] += val;
        __syncthreads();
    }
    int excl = sdata[t] - tsum;
    if (t == 255) bsum[blockIdx.x] = sdata[255];
    if (base + 0 < n) rp[base + 0] = excl;
    if (base + 1 < n) rp[base + 1] = excl + v0;
    if (base + 2 < n) rp[base + 2] = excl + v0 + v1;
    if (base + 3 < n) rp[base + 3] = excl + v0 + v1 + v2;
}

__global__ __launch_bounds__(128) void k_scan2(const int* __restrict__ bsum, int nb,
        int* __restrict__ boffs) {
    __shared__ int sd[128];
    int t = threadIdx.x;
    int v = (t < nb) ? bsum[t] : 0;
    sd[t] = v;
    __syncthreads();
    for (int off = 1; off < 128; off <<= 1) {
        int val = (t >= off) ? sd[t - off] : 0;
        __syncthreads();
        sd[t] += val;
        __syncthreads();
    }
    if (t < nb) boffs[t] = sd[t] - v;
}

__global__ __launch_bounds__(256) void k_scan3(int* __restrict__ rp, int n,
        const int* __restrict__ boffs, int E) {
    int i = blockIdx.x * blockDim.x + threadIdx.x;
    if (i < n) rp[i] += boffs[i / SCAN_ELEMS];
    if (i == 0) rp[n] = E;
}

__global__ __launch_bounds__(256) void k_fill(const int* __restrict__ src,
        const int* __restrict__ dst, const int* __restrict__ rank_, int E,
        const int* __restrict__ rp, int* __restrict__ col) {
    int e = blockIdx.x * blockDim.x + threadIdx.x;
    if (e < E) {
        __builtin_nontemporal_store(src[e], &col[rp[dst[e]] + rank_[e]]);
    }
}

// Layer-1 gather in padded 11->16 dim fp16 space: wave = 1 node, 4 edges per
// iteration (16 lanes per edge), unroll 2 -> 8 edges in flight. fp32 out.
__global__ __launch_bounds__(256, 8) void k_gather16(
        const unsigned short* __restrict__ x16h, float* __restrict__ h16,
        const int* __restrict__ rp, const int* __restrict__ col, int N) {
    int lane = threadIdx.x & 63, wv = threadIdx.x >> 6;
    int n = blockIdx.x * 4 + wv;
    if (n >= N) return;
    int sub = lane >> 4, c = lane & 15;
    int start = rp[n], end = rp[n + 1];
    float s0 = 0.f, s1 = 0.f;
    int eb = start;
    for (; eb + 8 <= end; eb += 8) {
        int j0 = col[eb + sub];
        int j1 = col[eb + 4 + sub];
        s0 += h2f(x16h[(size_t)j0 * 16 + c]);
        s1 += h2f(x16h[(size_t)j1 * 16 + c]);
    }
    for (int e = eb + sub; e < end; e += 4) {
        s0 += h2f(x16h[(size_t)col[e] * 16 + c]);
    }
    float s = s0 + s1;
    s += __shfl_xor(s, 16);
    s += __shfl_xor(s, 32);
    if (lane < 16) {
        h16[(size_t)n * 16 + lane] = s + h2f(x16h[(size_t)n * 16 + lane]);
    }
}

// Gather (layers 2-5): one wave per node, lane = channel, fp16 in/out.
// s = v_n + sum_j v_j; h2 = a*s + b*(1+deg) in fp32; agg stored fp16.
__global__ __launch_bounds__(256, 8) void k_gather(
        const unsigned short* __restrict__ vin, unsigned short* __restrict__ aggh,
        const int* __restrict__ rp, const int* __restrict__ col,
        const float* __restrict__ ab_prev, int N) {
    int lane = threadIdx.x & 63, wv = threadIdx.x >> 6;
    int n = blockIdx.x * 4 + wv;
    if (n >= N) return;
    float a = ab_prev[lane];
    float b = ab_prev[64 + lane];
    int start = rp[n], end = rp[n + 1];
    float s0 = h2f(vin[(size_t)n * 64 + lane]);
    float s1 = 0.f, s2 = 0.f, s3 = 0.f, s4 = 0.f, s5 = 0.f, s6 = 0.f, s7 = 0.f;
    int e = start;
    for (; e + 8 <= end; e += 8) {
        int j0 = col[e + 0], j1 = col[e + 1], j2 = col[e + 2], j3 = col[e + 3];
        int j4 = col[e + 4], j5 = col[e + 5], j6 = col[e + 6], j7 = col[e + 7];
        s0 += h2f(vin[(size_t)j0 * 64 + lane]);
        s1 += h2f(vin[(size_t)j1 * 64 + lane]);
        s2 += h2f(vin[(size_t)j2 * 64 + lane]);
        s3 += h2f(vin[(size_t)j3 * 64 + lane]);
        s4 += h2f(vin[(size_t)j4 * 64 + lane]);
        s5 += h2f(vin[(size_t)j5 * 64 + lane]);
        s6 += h2f(vin[(size_t)j6 * 64 + lane]);
        s7 += h2f(vin[(size_t)j7 * 64 + lane]);
    }
    for (; e < end; ++e) s0 += h2f(vin[(size_t)col[e] * 64 + lane]);
    float s = ((s0 + s1) + (s2 + s3)) + ((s4 + s5) + (s6 + s7));
    float h2 = fmaf(a, s, b * (float)(1 + end - start));
    aggh[(size_t)n * 64 + lane] = f2h(h2);
}

// MLP: one block = one 64-node tile. k-chunked matvecs; weights via the
// scalar pipe. fp16 in (agg) / fp16 out (v). fp32 stats + pooling.
template <bool FIRST>
__global__ __launch_bounds__(256, 4) void k_mlp(
        const void* __restrict__ aggp, unsigned short* __restrict__ vout,
        const int* __restrict__ batch,
        const float* __restrict__ Wa, const float* __restrict__ ba,
        const float* __restrict__ Wb, const float* __restrict__ bb,
        float* __restrict__ Sg, float* __restrict__ bnpart,
        int N) {
    __shared__ float hb[64 * 64];
    float4* hb4 = (float4*)hb;
    const int tid = threadIdx.x;
    const int lane = tid & 63;
    const int wv = tid >> 6;
    const int n0 = blockIdx.x * 64;
    const int l15 = lane & 15;
    // wave-uniform channel base, provably uniform -> weight reads use s_load
    const int c0 = __builtin_amdgcn_readfirstlane(wv) * 16;

    float acc[16];

    if (FIRST) {
        // ---- phase A': h16 (fp32 Nx16) -> transposed LDS hs[k][node] ----
        const float* h16 = (const float*)aggp;
        float* hs = hb;
        {
            int n = tid >> 2, kq = tid & 3;
            float4 v = make_float4(0.f, 0.f, 0.f, 0.f);
            if (n0 + n < N) v = ((const float4*)h16)[(size_t)n0 * 4 + tid];
            hs[(kq * 4 + 0) * 64 + n] = v.x;
            hs[(kq * 4 + 1) * 64 + n] = v.y;
            hs[(kq * 4 + 2) * 64 + n] = v.z;
            hs[(kq * 4 + 3) * 64 + n] = v.w;
        }
        __syncthreads();
        // ---- matvec1: t[c0+j] = relu(sum_{k<11} h[k]*W1a[k][c0+j] + ba) ----
#pragma unroll
        for (int j = 0; j < 16; ++j) acc[j] = ba[c0 + j];
#pragma unroll
        for (int k = 0; k < 11; ++k) {
            float hk = hs[k * 64 + lane];            // conflict-free
            const float* wr = Wa + k * 64 + c0;      // uniform -> s_load
#pragma unroll
            for (int j = 0; j < 16; ++j) acc[j] = fmaf(hk, wr[j], acc[j]);
        }
        __syncthreads();   // done reading hs; safe to overwrite hb
#pragma unroll
        for (int j4 = 0; j4 < 4; ++j4) {
            int q = wv * 4 + j4;
            hb4[lane * 16 + (q ^ l15)] = make_float4(
                fmaxf(acc[j4 * 4 + 0], 0.f), fmaxf(acc[j4 * 4 + 1], 0.f),
                fmaxf(acc[j4 * 4 + 2], 0.f), fmaxf(acc[j4 * 4 + 3], 0.f));
        }
        __syncthreads();
    } else {
        // ---- phase A: fp16 tile (uint4 = 8ch) -> LDS (swizzled fp32) ----
        {
            const unsigned short* aggh = (const unsigned short*)aggp;
            const uint4* a4 = (const uint4*)(aggh + (size_t)n0 * 64);
#pragma unroll
            for (int r = 0; r < 2; ++r) {
                int i = tid + r * 256;          // ushort8 index within tile
                int nt = i >> 3, q8 = i & 7;
                uint4 u = make_uint4(0, 0, 0, 0);
                if (n0 + nt < N) u = a4[i];
                float4 v0, v1;
                v0.x = h2f((unsigned short)(u.x & 0xffff));
                v0.y = h2f((unsigned short)(u.x >> 16));
                v0.z = h2f((unsigned short)(u.y & 0xffff));
                v0.w = h2f((unsigned short)(u.y >> 16));
                v1.x = h2f((unsigned short)(u.z & 0xffff));
                v1.y = h2f((unsigned short)(u.z >> 16));
                v1.z = h2f((unsigned short)(u.w & 0xffff));
                v1.w = h2f((unsigned short)(u.w >> 16));
                int sw = nt & 15;
                hb4[nt * 16 + ((2 * q8 + 0) ^ sw)] = v0;
                hb4[nt * 16 + ((2 * q8 + 1) ^ sw)] = v1;
            }
        }
        __syncthreads();
        // ---- matvec1: t[c0+j] = relu(sum_k h[k]*Wa[k][c0+j] + ba[c0+j]) ----
#pragma unroll
        for (int j = 0; j < 16; ++j) acc[j] = ba[c0 + j];
        for (int kc = 0; kc < 4; ++kc) {
            float hq[16];
#pragma unroll
            for (int q4 = 0; q4 < 4; ++q4) {
                float4 hv = hb4[lane * 16 + ((kc * 4 + q4) ^ l15)];
                hq[q4 * 4 + 0] = hv.x; hq[q4 * 4 + 1] = hv.y;
                hq[q4 * 4 + 2] = hv.z; hq[q4 * 4 + 3] = hv.w;
            }
            const float* wbase = Wa + (size_t)(kc * 16) * 64 + c0;   // uniform
#pragma unroll
            for (int kk = 0; kk < 16; ++kk) {
                float w[16];
#pragma unroll
                for (int j = 0; j < 16; ++j) w[j] = wbase[kk * 64 + j];  // s_load
                float hk = hq[kk];
#pragma unroll
                for (int j = 0; j < 16; ++j) acc[j] = fmaf(hk, w[j], acc[j]);
            }
        }
        __syncthreads();   // everyone done reading h from hb
#pragma unroll
        for (int j4 = 0; j4 < 4; ++j4) {
            int q = wv * 4 + j4;
            hb4[lane * 16 + (q ^ l15)] = make_float4(
                fmaxf(acc[j4 * 4 + 0], 0.f), fmaxf(acc[j4 * 4 + 1], 0.f),
                fmaxf(acc[j4 * 4 + 2], 0.f), fmaxf(acc[j4 * 4 + 3], 0.f));
        }
        __syncthreads();
    }

    // ---- matvec2: v[c0+j] = relu(sum_k t[k]*Wb[k][c0+j] + bb[c0+j]) ----
#pragma unroll
    for (int j = 0; j < 16; ++j) acc[j] = bb[c0 + j];
    for (int kc = 0; kc < 4; ++kc) {
        float hq[16];
#pragma unroll
        for (int q4 = 0; q4 < 4; ++q4) {
            float4 hv = hb4[lane * 16 + ((kc * 4 + q4) ^ l15)];
            hq[q4 * 4 + 0] = hv.x; hq[q4 * 4 + 1] = hv.y;
            hq[q4 * 4 + 2] = hv.z; hq[q4 * 4 + 3] = hv.w;
        }
        const float* wbase = Wb + (size_t)(kc * 16) * 64 + c0;       // uniform
#pragma unroll
        for (int kk = 0; kk < 16; ++kk) {
            float w[16];
#pragma unroll
            for (int j = 0; j < 16; ++j) w[j] = wbase[kk * 64 + j];  // s_load
            float hk = hq[kk];
#pragma unroll
            for (int j = 0; j < 16; ++j) acc[j] = fmaf(hk, w[j], acc[j]);
        }
    }
    __syncthreads();   // everyone done reading hb
    {
#pragma unroll
        for (int j4 = 0; j4 < 4; ++j4) {
            int q = wv * 4 + j4;
            hb4[lane * 16 + (q ^ l15)] = make_float4(
                fmaxf(acc[j4 * 4 + 0], 0.f), fmaxf(acc[j4 * 4 + 1], 0.f),
                fmaxf(acc[j4 * 4 + 2], 0.f), fmaxf(acc[j4 * 4 + 3], 0.f));
        }
    }
    __syncthreads();

    // ---- phase C: fp16 store + BN stats + graph pooling (fp32) ----
    {
        int q = lane & 15;          // channel quad
        int ng = lane >> 4;         // node subgroup
        int base_nt = wv * 16;
        float4 bs = make_float4(0, 0, 0, 0), bq = make_float4(0, 0, 0, 0);

        bool full = (n0 + base_nt + 15) < N;            // wave-uniform
        int gf = 0, gl = -1;
        if (full) { gf = batch[n0 + base_nt]; gl = batch[n0 + base_nt + 15]; }

        if (full && gf == gl) {
            // fast path: whole 16-node group in one graph
            float4 pacc = make_float4(0, 0, 0, 0);
#pragma unroll
            for (int s2 = 0; s2 < 4; ++s2) {
                int nt = base_nt + s2 * 4 + ng;
                float4 v = hb4[nt * 16 + (q ^ (nt & 15))];
                ushort4 o;
                o.x = f2h(v.x); o.y = f2h(v.y); o.z = f2h(v.z); o.w = f2h(v.w);
                *(ushort4*)(vout + (size_t)(n0 + nt) * 64 + q * 4) = o;
                bs.x += v.x; bs.y += v.y; bs.z += v.z; bs.w += v.w;
                bq.x += v.x * v.x; bq.y += v.y * v.y;
                bq.z += v.z * v.z; bq.w += v.w * v.w;
                pacc.x += v.x; pacc.y += v.y; pacc.z += v.z; pacc.w += v.w;
            }
#pragma unroll
            for (int off = 16; off < 64; off <<= 1) {
                pacc.x += __shfl_xor(pacc.x, off); pacc.y += __shfl_xor(pacc.y, off);
                pacc.z += __shfl_xor(pacc.z, off); pacc.w += __shfl_xor(pacc.w, off);
            }
            if (ng == 0) {
                atomicAdd(&Sg[gf * 64 + q * 4 + 0], pacc.x);
                atomicAdd(&Sg[gf * 64 + q * 4 + 1], pacc.y);
                atomicAdd(&Sg[gf * 64 + q * 4 + 2], pacc.z);
                atomicAdd(&Sg[gf * 64 + q * 4 + 3], pacc.w);
            }
        } else {
            // slow path: graph boundary inside the group (or tile tail)
            float4 pacc = make_float4(0, 0, 0, 0);
            int curg = -1;
#pragma unroll
            for (int s2 = 0; s2 < 4; ++s2) {
                int nt = base_nt + s2 * 4 + ng;
                int n = n0 + nt;
                if (n < N) {
                    float4 v = hb4[nt * 16 + (q ^ (nt & 15))];
                    ushort4 o;
                    o.x = f2h(v.x); o.y = f2h(v.y); o.z = f2h(v.z); o.w = f2h(v.w);
                    *(ushort4*)(vout + (size_t)n * 64 + q * 4) = o;
                    bs.x += v.x; bs.y += v.y; bs.z += v.z; bs.w += v.w;
                    bq.x += v.x * v.x; bq.y += v.y * v.y;
                    bq.z += v.z * v.z; bq.w += v.w * v.w;
                    int g = batch[n];
                    if (g != curg) {
                        if (curg >= 0) {
                            atomicAdd(&Sg[curg * 64 + q * 4 + 0], pacc.x);
                            atomicAdd(&Sg[curg * 64 + q * 4 + 1], pacc.y);
                            atomicAdd(&Sg[curg * 64 + q * 4 + 2], pacc.z);
                            atomicAdd(&Sg[curg * 64 + q * 4 + 3], pacc.w);
                        }
                        curg = g;
                        pacc = make_float4(0, 0, 0, 0);
                    }
                    pacc.x += v.x; pacc.y += v.y; pacc.z += v.z; pacc.w += v.w;
                }
            }
            if (curg >= 0) {
                atomicAdd(&Sg[curg * 64 + q * 4 + 0], pacc.x);
                atomicAdd(&Sg[curg * 64 + q * 4 + 1], pacc.y);
                atomicAdd(&Sg[curg * 64 + q * 4 + 2], pacc.z);
                atomicAdd(&Sg[curg * 64 + q * 4 + 3], pacc.w);
            }
        }
#pragma unroll
        for (int off = 16; off < 64; off <<= 1) {
            bs.x += __shfl_xor(bs.x, off); bs.y += __shfl_xor(bs.y, off);
            bs.z += __shfl_xor(bs.z, off); bs.w += __shfl_xor(bs.w, off);
            bq.x += __shfl_xor(bq.x, off); bq.y += __shfl_xor(bq.y, off);
            bq.z += __shfl_xor(bq.z, off); bq.w += __shfl_xor(bq.w, off);
        }
        if (ng == 0) {
            float* bkt = bnpart + (blockIdx.x & 31) * 128;
            atomicAdd(&bkt[q * 4 + 0], bs.x);
            atomicAdd(&bkt[q * 4 + 1], bs.y);
            atomicAdd(&bkt[q * 4 + 2], bs.z);
            atomicAdd(&bkt[q * 4 + 3], bs.w);
            atomicAdd(&bkt[64 + q * 4 + 0], bq.x);
            atomicAdd(&bkt[64 + q * 4 + 1], bq.y);
            atomicAdd(&bkt[64 + q * 4 + 2], bq.z);
            atomicAdd(&bkt[64 + q * 4 + 3], bq.w);
        }
    }
}

__global__ void k_bnstat(const float* __restrict__ bnpart,
        const float* __restrict__ gamma, const float* __restrict__ beta,
        float* __restrict__ a, float* __restrict__ b, int N) {
    int c = threadIdx.x;  // 64 threads
    float s = 0.f, q = 0.f;
    for (int i = 0; i < 32; ++i) { s += bnpart[i * 128 + c]; q += bnpart[i * 128 + 64 + c]; }
    float invN = 1.0f / (float)N;
    float mu = s * invN;
    float var = q * invN - mu * mu;
    float ac = gamma[c] * rsqrtf(var + 1e-5f);
    a[c] = ac;
    b[c] = beta[c] - mu * ac;
}

// Head: z[g,320] = concat_l (a_l*S_l[g] + b_l*cnt[g]); out = relu(z@fc1+b)@fc2+b
__global__ __launch_bounds__(256) void k_final(
        const float* __restrict__ S, const float* __restrict__ ab,
        const int* __restrict__ cntg,
        const float* __restrict__ fc1W, const float* __restrict__ fc1b,
        const float* __restrict__ fc2W, const float* __restrict__ fc2b,
        float* __restrict__ out, int G) {
    __shared__ float zbuf[4][320];
    int tid = threadIdx.x;
    int lane = tid & 63, wv = tid >> 6;
    int g = blockIdx.x * 4 + wv;
    if (g >= G) return;
    float cf = (float)cntg[g];
#pragma unroll
    for (int l = 0; l < 5; ++l) {
        float a = ab[l * 128 + lane];
        float b = ab[l * 128 + 64 + lane];
        zbuf[wv][l * 64 + lane] = a * S[((size_t)l * G + g) * 64 + lane] + b * cf;
    }
    float acc = fc1b[lane];
    for (int k = 0; k < 320; ++k) acc += zbuf[wv][k] * fc1W[k * 64 + lane];
    float t = fmaxf(acc, 0.f);
    float r = t * fc2W[lane];
#pragma unroll
    for (int off = 32; off >= 1; off >>= 1) r += __shfl_xor(r, off);
    if (lane == 0) out[g] = r + fc2b[0];
}

extern "C" void kernel_launch(void* const* d_in, const int* in_sizes, int n_in,
                              void* d_out, int out_size, void* d_ws, size_t ws_size,
                              hipStream_t stream) {
    const float* x    = (const float*)d_in[0];
    const int*   ei   = (const int*)d_in[1];
    const int*   batch= (const int*)d_in[2];
    const float* W1a  = (const float*)d_in[3];
    const float* b1a  = (const float*)d_in[4];
    const float* W1b  = (const float*)d_in[5];
    const float* b1b  = (const float*)d_in[6];
    const float* Wa   = (const float*)d_in[7];
    const float* ba   = (const float*)d_in[8];
    const float* Wb   = (const float*)d_in[9];
    const float* bb   = (const float*)d_in[10];
    const float* gamma= (const float*)d_in[11];
    const float* beta = (const float*)d_in[12];
    const float* fc1W = (const float*)d_in[13];
    const float* fc1b = (const float*)d_in[14];
    const float* fc2W = (const float*)d_in[15];
    const float* fc2b = (const float*)d_in[16];

    const int N = in_sizes[2];
    const int E = in_sizes[1] / 2;
    const int G = out_size;
    const int* srcp = ei;
    const int* dstp = ei + E;

    char* p = (char*)d_ws;
    auto alloc = [&](size_t bytes) {
        char* r = p;
        p += (bytes + 255) & ~size_t(255);
        return r;
    };
    unsigned short* aggh = (unsigned short*)alloc((size_t)N * 64 * 2);
    unsigned short* vb   = (unsigned short*)alloc((size_t)N * 64 * 2);
    int*   col    = (int*)  alloc((size_t)E * 4);
    int*   rank_  = (int*)  alloc((size_t)E * 4);
    int*   rp     = (int*)  alloc((size_t)(N + 1) * 4);
    unsigned short* x16h = (unsigned short*)alloc((size_t)N * 16 * 2);
    float* h16    = (float*)alloc((size_t)N * 16 * 4);
    int*   bsum   = (int*)  alloc(512);
    int*   boffs  = (int*)  alloc(512);
    float* ab     = (float*)alloc(5 * 128 * 4);
    // ---- zeroed region (single memset) ----
    char*  z0     = p;
    int*   cntn   = (int*)  alloc((size_t)N * 4);
    int*   cntg   = (int*)  alloc((size_t)G * 4);
    float* S      = (float*)alloc((size_t)5 * G * 64 * 4);
    float* bnpart = (float*)alloc((size_t)5 * 32 * 128 * 4);
    size_t zbytes = (size_t)(p - z0);

    hipMemsetAsync(z0, 0, zbytes, stream);

    int nb_e = (E + 255) / 256;
    int nb_scan = (N + SCAN_ELEMS - 1) / SCAN_ELEMS;
    k_hist<<<nb_e, 256, 0, stream>>>(dstp, E, cntn, rank_, batch, N, cntg, x, x16h);
    k_scan1<<<nb_scan, 256, 0, stream>>>(cntn, N, rp, bsum);
    k_scan2<<<1, 128, 0, stream>>>(bsum, nb_scan, boffs);
    k_scan3<<<(N + 255) / 256, 256, 0, stream>>>(rp, N, boffs, E);
    k_fill<<<nb_e, 256, 0, stream>>>(srcp, dstp, rank_, E, rp, col);

    int nb_node = (N + 3) / 4;
    int nb_tile = (N + 63) / 64;

    // Layer 1: 16-dim fp16 gather, then mlp<FIRST> does W1a from h16 (fp32)
    k_gather16<<<nb_node, 256, 0, stream>>>(x16h, h16, rp, col, N);
    k_mlp<true><<<nb_tile, 256, 0, stream>>>(h16, vb, batch,
        W1a, b1a, W1b, b1b, S, bnpart, N);
    k_bnstat<<<1, 64, 0, stream>>>(bnpart, gamma, beta, ab, ab + 64, N);

    for (int l = 0; l < 4; ++l) {
        k_gather<<<nb_node, 256, 0, stream>>>(vb, aggh, rp, col,
            ab + l * 128, N);
        k_mlp<false><<<nb_tile, 256, 0, stream>>>(aggh, vb, batch,
            Wa + l * 4096, ba + l * 64, Wb + l * 4096, bb + l * 64,
            S + (size_t)(l + 1) * G * 64,
            bnpart + (size_t)(l + 1) * 32 * 128, N);
        k_bnstat<<<1, 64, 0, stream>>>(
            bnpart + (size_t)(l + 1) * 32 * 128,
            gamma + (l + 1) * 64, beta + (l + 1) * 64,
            ab + (l + 1) * 128, ab + (l + 1) * 128 + 64, N);
    }

    k_final<<<(G + 3) / 4, 256, 0, stream>>>(S, ab, cntg, fc1W, fc1b, fc2W, fc2b,
                                             (float*)d_out, G);
}

// Round 12
// 761.730 us; speedup vs baseline: 1.9715x; 1.0468x over previous
//
#include <hip/hip_runtime.h>
#include <hip/hip_fp16.h>

// ---------------------------------------------------------------------------
// GIN (5 layers) + BN + graph pooling + MLP head.
// R12: (1) k_prep split back out of k_hist (R11 merged them: 107us vs 66+12
//      split -- node work interleaved into the atomic stream is expensive).
//      (2) gather ILP deepened 8->16 (more loads in flight vs ~400cyc L2/L3
//      latency). (3) k_gather16 likewise 4-deep per lane.
//      Everything else identical to R11 (797us, absmax 0.0625).
// ---------------------------------------------------------------------------

#define SCAN_ELEMS 1024

__device__ __forceinline__ unsigned short f2h(float f) {
    return __half_as_ushort(__float2half_rn(f));
}
__device__ __forceinline__ float h2f(unsigned short s) {
    return __half2float(__ushort_as_half(s));
}

// Edge-only histogram + rank (atomic returns slot)
__global__ __launch_bounds__(256) void k_hist(const int* __restrict__ dst, int E,
        int* __restrict__ cnt_node, int* __restrict__ rank_) {
    int i = blockIdx.x * blockDim.x + threadIdx.x;
    if (i < E) rank_[i] = atomicAdd(&cnt_node[dst[i]], 1);
}

// Node prep: x -> fp16 padded 16ch, graph counts
__global__ __launch_bounds__(256) void k_prep(const float* __restrict__ x,
        unsigned short* __restrict__ x16h, const int* __restrict__ batch,
        int* __restrict__ cnt_graph, int N) {
    int i = blockIdx.x * blockDim.x + threadIdx.x;
    if (i < N) {
        atomicAdd(&cnt_graph[batch[i]], 1);
#pragma unroll
        for (int k = 0; k < 11; ++k) x16h[i * 16 + k] = f2h(x[i * 11 + k]);
#pragma unroll
        for (int k = 11; k < 16; ++k) x16h[i * 16 + k] = 0;
    }
}

__global__ __launch_bounds__(256) void k_scan1(const int* __restrict__ cnt, int n,
        int* __restrict__ rp, int* __restrict__ bsum) {
    __shared__ int sdata[256];
    int t = threadIdx.x;
    int base = blockIdx.x * SCAN_ELEMS + t * 4;
    int v0 = (base + 0 < n) ? cnt[base + 0] : 0;
    int v1 = (base + 1 < n) ? cnt[base + 1] : 0;
    int v2 = (base + 2 < n) ? cnt[base + 2] : 0;
    int v3 = (base + 3 < n) ? cnt[base + 3] : 0;
    int tsum = v0 + v1 + v2 + v3;
    sdata[t] = tsum;
    __syncthreads();
    for (int off = 1; off < 256; off <<= 1) {
        int val = (t >= off) ? sdata[t - off] : 0;
        __syncthreads();
        sdata[t] += val;
        __syncthreads();
    }
    int excl = sdata[t] - tsum;
    if (t == 255) bsum[blockIdx.x] = sdata[255];
    if (base + 0 < n) rp[base + 0] = excl;
    if (base + 1 < n) rp[base + 1] = excl + v0;
    if (base + 2 < n) rp[base + 2] = excl + v0 + v1;
    if (base + 3 < n) rp[base + 3] = excl + v0 + v1 + v2;
}

__global__ __launch_bounds__(128) void k_scan2(const int* __restrict__ bsum, int nb,
        int* __restrict__ boffs) {
    __shared__ int sd[128];
    int t = threadIdx.x;
    int v = (t < nb) ? bsum[t] : 0;
    sd[t] = v;
    __syncthreads();
    for (int off = 1; off < 128; off <<= 1) {
        int val = (t >= off) ? sd[t - off] : 0;
        __syncthreads();
        sd[t] += val;
        __syncthreads();
    }
    if (t < nb) boffs[t] = sd[t] - v;
}

__global__ __launch_bounds__(256) void k_scan3(int* __restrict__ rp, int n,
        const int* __restrict__ boffs, int E) {
    int i = blockIdx.x * blockDim.x + threadIdx.x;
    if (i < n) rp[i] += boffs[i / SCAN_ELEMS];
    if (i == 0) rp[n] = E;
}

__global__ __launch_bounds__(256) void k_fill(const int* __restrict__ src,
        const int* __restrict__ dst, const int* __restrict__ rank_, int E,
        const int* __restrict__ rp, int* __restrict__ col) {
    int e = blockIdx.x * blockDim.x + threadIdx.x;
    if (e < E) {
        __builtin_nontemporal_store(src[e], &col[rp[dst[e]] + rank_[e]]);
    }
}

// Layer-1 gather in padded 11->16 dim fp16 space: wave = 1 node, 4 edges per
// step (16 lanes per edge), 4-deep -> 16 edges in flight. fp32 out.
__global__ __launch_bounds__(256, 8) void k_gather16(
        const unsigned short* __restrict__ x16h, float* __restrict__ h16,
        const int* __restrict__ rp, const int* __restrict__ col, int N) {
    int lane = threadIdx.x & 63, wv = threadIdx.x >> 6;
    int n = blockIdx.x * 4 + wv;
    if (n >= N) return;
    int sub = lane >> 4, c = lane & 15;
    int start = rp[n], end = rp[n + 1];
    float s0 = 0.f, s1 = 0.f, s2 = 0.f, s3 = 0.f;
    int eb = start;
    for (; eb + 16 <= end; eb += 16) {
        int j0 = col[eb + sub];
        int j1 = col[eb + 4 + sub];
        int j2 = col[eb + 8 + sub];
        int j3 = col[eb + 12 + sub];
        s0 += h2f(x16h[(size_t)j0 * 16 + c]);
        s1 += h2f(x16h[(size_t)j1 * 16 + c]);
        s2 += h2f(x16h[(size_t)j2 * 16 + c]);
        s3 += h2f(x16h[(size_t)j3 * 16 + c]);
    }
    for (; eb + 4 <= end; eb += 4) {
        int j0 = col[eb + sub];
        s0 += h2f(x16h[(size_t)j0 * 16 + c]);
    }
    for (int e = eb + sub; e < end; e += 4) {
        s1 += h2f(x16h[(size_t)col[e] * 16 + c]);
    }
    float s = (s0 + s1) + (s2 + s3);
    s += __shfl_xor(s, 16);
    s += __shfl_xor(s, 32);
    if (lane < 16) {
        h16[(size_t)n * 16 + lane] = s + h2f(x16h[(size_t)n * 16 + lane]);
    }
}

// Gather (layers 2-5): one wave per node, lane = channel, fp16 in/out.
// s = v_n + sum_j v_j; h2 = a*s + b*(1+deg) in fp32; 16-deep load ILP.
__global__ __launch_bounds__(256, 8) void k_gather(
        const unsigned short* __restrict__ vin, unsigned short* __restrict__ aggh,
        const int* __restrict__ rp, const int* __restrict__ col,
        const float* __restrict__ ab_prev, int N) {
    int lane = threadIdx.x & 63, wv = threadIdx.x >> 6;
    int n = blockIdx.x * 4 + wv;
    if (n >= N) return;
    float a = ab_prev[lane];
    float b = ab_prev[64 + lane];
    int start = rp[n], end = rp[n + 1];
    float s[16];
#pragma unroll
    for (int u = 0; u < 16; ++u) s[u] = 0.f;
    s[0] = h2f(vin[(size_t)n * 64 + lane]);
    int e = start;
    for (; e + 16 <= end; e += 16) {
        int j[16];
#pragma unroll
        for (int u = 0; u < 16; ++u) j[u] = col[e + u];
#pragma unroll
        for (int u = 0; u < 16; ++u)
            s[u] += h2f(vin[(size_t)j[u] * 64 + lane]);
    }
    for (; e + 4 <= end; e += 4) {
        int j0 = col[e + 0], j1 = col[e + 1], j2 = col[e + 2], j3 = col[e + 3];
        s[0] += h2f(vin[(size_t)j0 * 64 + lane]);
        s[1] += h2f(vin[(size_t)j1 * 64 + lane]);
        s[2] += h2f(vin[(size_t)j2 * 64 + lane]);
        s[3] += h2f(vin[(size_t)j3 * 64 + lane]);
    }
    for (; e < end; ++e) s[0] += h2f(vin[(size_t)col[e] * 64 + lane]);
#pragma unroll
    for (int u = 8; u > 0; u >>= 1)
#pragma unroll
        for (int v2 = 0; v2 < u; ++v2) s[v2] += s[v2 + u];
    float h2 = fmaf(a, s[0], b * (float)(1 + end - start));
    aggh[(size_t)n * 64 + lane] = f2h(h2);
}

// MLP: one block = one 64-node tile. k-chunked matvecs; weights via the
// scalar pipe. fp16 in (agg) / fp16 out (v). fp32 stats + pooling.
template <bool FIRST>
__global__ __launch_bounds__(256, 4) void k_mlp(
        const void* __restrict__ aggp, unsigned short* __restrict__ vout,
        const int* __restrict__ batch,
        const float* __restrict__ Wa, const float* __restrict__ ba,
        const float* __restrict__ Wb, const float* __restrict__ bb,
        float* __restrict__ Sg, float* __restrict__ bnpart,
        int N) {
    __shared__ float hb[64 * 64];
    float4* hb4 = (float4*)hb;
    const int tid = threadIdx.x;
    const int lane = tid & 63;
    const int wv = tid >> 6;
    const int n0 = blockIdx.x * 64;
    const int l15 = lane & 15;
    // wave-uniform channel base, provably uniform -> weight reads use s_load
    const int c0 = __builtin_amdgcn_readfirstlane(wv) * 16;

    float acc[16];

    if (FIRST) {
        // ---- phase A': h16 (fp32 Nx16) -> transposed LDS hs[k][node] ----
        const float* h16 = (const float*)aggp;
        float* hs = hb;
        {
            int n = tid >> 2, kq = tid & 3;
            float4 v = make_float4(0.f, 0.f, 0.f, 0.f);
            if (n0 + n < N) v = ((const float4*)h16)[(size_t)n0 * 4 + tid];
            hs[(kq * 4 + 0) * 64 + n] = v.x;
            hs[(kq * 4 + 1) * 64 + n] = v.y;
            hs[(kq * 4 + 2) * 64 + n] = v.z;
            hs[(kq * 4 + 3) * 64 + n] = v.w;
        }
        __syncthreads();
        // ---- matvec1: t[c0+j] = relu(sum_{k<11} h[k]*W1a[k][c0+j] + ba) ----
#pragma unroll
        for (int j = 0; j < 16; ++j) acc[j] = ba[c0 + j];
#pragma unroll
        for (int k = 0; k < 11; ++k) {
            float hk = hs[k * 64 + lane];            // conflict-free
            const float* wr = Wa + k * 64 + c0;      // uniform -> s_load
#pragma unroll
            for (int j = 0; j < 16; ++j) acc[j] = fmaf(hk, wr[j], acc[j]);
        }
        __syncthreads();   // done reading hs; safe to overwrite hb
#pragma unroll
        for (int j4 = 0; j4 < 4; ++j4) {
            int q = wv * 4 + j4;
            hb4[lane * 16 + (q ^ l15)] = make_float4(
                fmaxf(acc[j4 * 4 + 0], 0.f), fmaxf(acc[j4 * 4 + 1], 0.f),
                fmaxf(acc[j4 * 4 + 2], 0.f), fmaxf(acc[j4 * 4 + 3], 0.f));
        }
        __syncthreads();
    } else {
        // ---- phase A: fp16 tile (uint4 = 8ch) -> LDS (swizzled fp32) ----
        {
            const unsigned short* aggh = (const unsigned short*)aggp;
            const uint4* a4 = (const uint4*)(aggh + (size_t)n0 * 64);
#pragma unroll
            for (int r = 0; r < 2; ++r) {
                int i = tid + r * 256;          // ushort8 index within tile
                int nt = i >> 3, q8 = i & 7;
                uint4 u = make_uint4(0, 0, 0, 0);
                if (n0 + nt < N) u = a4[i];
                float4 v0, v1;
                v0.x = h2f((unsigned short)(u.x & 0xffff));
                v0.y = h2f((unsigned short)(u.x >> 16));
                v0.z = h2f((unsigned short)(u.y & 0xffff));
                v0.w = h2f((unsigned short)(u.y >> 16));
                v1.x = h2f((unsigned short)(u.z & 0xffff));
                v1.y = h2f((unsigned short)(u.z >> 16));
                v1.z = h2f((unsigned short)(u.w & 0xffff));
                v1.w = h2f((unsigned short)(u.w >> 16));
                int sw = nt & 15;
                hb4[nt * 16 + ((2 * q8 + 0) ^ sw)] = v0;
                hb4[nt * 16 + ((2 * q8 + 1) ^ sw)] = v1;
            }
        }
        __syncthreads();
        // ---- matvec1: t[c0+j] = relu(sum_k h[k]*Wa[k][c0+j] + ba[c0+j]) ----
#pragma unroll
        for (int j = 0; j < 16; ++j) acc[j] = ba[c0 + j];
        for (int kc = 0; kc < 4; ++kc) {
            float hq[16];
#pragma unroll
            for (int q4 = 0; q4 < 4; ++q4) {
                float4 hv = hb4[lane * 16 + ((kc * 4 + q4) ^ l15)];
                hq[q4 * 4 + 0] = hv.x; hq[q4 * 4 + 1] = hv.y;
                hq[q4 * 4 + 2] = hv.z; hq[q4 * 4 + 3] = hv.w;
            }
            const float* wbase = Wa + (size_t)(kc * 16) * 64 + c0;   // uniform
#pragma unroll
            for (int kk = 0; kk < 16; ++kk) {
                float w[16];
#pragma unroll
                for (int j = 0; j < 16; ++j) w[j] = wbase[kk * 64 + j];  // s_load
                float hk = hq[kk];
#pragma unroll
                for (int j = 0; j < 16; ++j) acc[j] = fmaf(hk, w[j], acc[j]);
            }
        }
        __syncthreads();   // everyone done reading h from hb
#pragma unroll
        for (int j4 = 0; j4 < 4; ++j4) {
            int q = wv * 4 + j4;
            hb4[lane * 16 + (q ^ l15)] = make_float4(
                fmaxf(acc[j4 * 4 + 0], 0.f), fmaxf(acc[j4 * 4 + 1], 0.f),
                fmaxf(acc[j4 * 4 + 2], 0.f), fmaxf(acc[j4 * 4 + 3], 0.f));
        }
        __syncthreads();
    }

    // ---- matvec2: v[c0+j] = relu(sum_k t[k]*Wb[k][c0+j] + bb[c0+j]) ----
#pragma unroll
    for (int j = 0; j < 16; ++j) acc[j] = bb[c0 + j];
    for (int kc = 0; kc < 4; ++kc) {
        float hq[16];
#pragma unroll
        for (int q4 = 0; q4 < 4; ++q4) {
            float4 hv = hb4[lane * 16 + ((kc * 4 + q4) ^ l15)];
            hq[q4 * 4 + 0] = hv.x; hq[q4 * 4 + 1] = hv.y;
            hq[q4 * 4 + 2] = hv.z; hq[q4 * 4 + 3] = hv.w;
        }
        const float* wbase = Wb + (size_t)(kc * 16) * 64 + c0;       // uniform
#pragma unroll
        for (int kk = 0; kk < 16; ++kk) {
            float w[16];
#pragma unroll
            for (int j = 0; j < 16; ++j) w[j] = wbase[kk * 64 + j];  // s_load
            float hk = hq[kk];
#pragma unroll
            for (int j = 0; j < 16; ++j) acc[j] = fmaf(hk, w[j], acc[j]);
        }
    }
    __syncthreads();   // everyone done reading hb
    {
#pragma unroll
        for (int j4 = 0; j4 < 4; ++j4) {
            int q = wv * 4 + j4;
            hb4[lane * 16 + (q ^ l15)] = make_float4(
                fmaxf(acc[j4 * 4 + 0], 0.f), fmaxf(acc[j4 * 4 + 1], 0.f),
                fmaxf(acc[j4 * 4 + 2], 0.f), fmaxf(acc[j4 * 4 + 3], 0.f));
        }
    }
    __syncthreads();

    // ---- phase C: fp16 store + BN stats + graph pooling (fp32) ----
    {
        int q = lane & 15;          // channel quad
        int ng = lane >> 4;         // node subgroup
        int base_nt = wv * 16;
        float4 bs = make_float4(0, 0, 0, 0), bq = make_float4(0, 0, 0, 0);

        bool full = (n0 + base_nt + 15) < N;            // wave-uniform
        int gf = 0, gl = -1;
        if (full) { gf = batch[n0 + base_nt]; gl = batch[n0 + base_nt + 15]; }

        if (full && gf == gl) {
            // fast path: whole 16-node group in one graph
            float4 pacc = make_float4(0, 0, 0, 0);
#pragma unroll
            for (int s2 = 0; s2 < 4; ++s2) {
                int nt = base_nt + s2 * 4 + ng;
                float4 v = hb4[nt * 16 + (q ^ (nt & 15))];
                ushort4 o;
                o.x = f2h(v.x); o.y = f2h(v.y); o.z = f2h(v.z); o.w = f2h(v.w);
                *(ushort4*)(vout + (size_t)(n0 + nt) * 64 + q * 4) = o;
                bs.x += v.x; bs.y += v.y; bs.z += v.z; bs.w += v.w;
                bq.x += v.x * v.x; bq.y += v.y * v.y;
                bq.z += v.z * v.z; bq.w += v.w * v.w;
                pacc.x += v.x; pacc.y += v.y; pacc.z += v.z; pacc.w += v.w;
            }
#pragma unroll
            for (int off = 16; off < 64; off <<= 1) {
                pacc.x += __shfl_xor(pacc.x, off); pacc.y += __shfl_xor(pacc.y, off);
                pacc.z += __shfl_xor(pacc.z, off); pacc.w += __shfl_xor(pacc.w, off);
            }
            if (ng == 0) {
                atomicAdd(&Sg[gf * 64 + q * 4 + 0], pacc.x);
                atomicAdd(&Sg[gf * 64 + q * 4 + 1], pacc.y);
                atomicAdd(&Sg[gf * 64 + q * 4 + 2], pacc.z);
                atomicAdd(&Sg[gf * 64 + q * 4 + 3], pacc.w);
            }
        } else {
            // slow path: graph boundary inside the group (or tile tail)
            float4 pacc = make_float4(0, 0, 0, 0);
            int curg = -1;
#pragma unroll
            for (int s2 = 0; s2 < 4; ++s2) {
                int nt = base_nt + s2 * 4 + ng;
                int n = n0 + nt;
                if (n < N) {
                    float4 v = hb4[nt * 16 + (q ^ (nt & 15))];
                    ushort4 o;
                    o.x = f2h(v.x); o.y = f2h(v.y); o.z = f2h(v.z); o.w = f2h(v.w);
                    *(ushort4*)(vout + (size_t)n * 64 + q * 4) = o;
                    bs.x += v.x; bs.y += v.y; bs.z += v.z; bs.w += v.w;
                    bq.x += v.x * v.x; bq.y += v.y * v.y;
                    bq.z += v.z * v.z; bq.w += v.w * v.w;
                    int g = batch[n];
                    if (g != curg) {
                        if (curg >= 0) {
                            atomicAdd(&Sg[curg * 64 + q * 4 + 0], pacc.x);
                            atomicAdd(&Sg[curg * 64 + q * 4 + 1], pacc.y);
                            atomicAdd(&Sg[curg * 64 + q * 4 + 2], pacc.z);
                            atomicAdd(&Sg[curg * 64 + q * 4 + 3], pacc.w);
                        }
                        curg = g;
                        pacc = make_float4(0, 0, 0, 0);
                    }
                    pacc.x += v.x; pacc.y += v.y; pacc.z += v.z; pacc.w += v.w;
                }
            }
            if (curg >= 0) {
                atomicAdd(&Sg[curg * 64 + q * 4 + 0], pacc.x);
                atomicAdd(&Sg[curg * 64 + q * 4 + 1], pacc.y);
                atomicAdd(&Sg[curg * 64 + q * 4 + 2], pacc.z);
                atomicAdd(&Sg[curg * 64 + q * 4 + 3], pacc.w);
            }
        }
#pragma unroll
        for (int off = 16; off < 64; off <<= 1) {
            bs.x += __shfl_xor(bs.x, off); bs.y += __shfl_xor(bs.y, off);
            bs.z += __shfl_xor(bs.z, off); bs.w += __shfl_xor(bs.w, off);
            bq.x += __shfl_xor(bq.x, off); bq.y += __shfl_xor(bq.y, off);
            bq.z += __shfl_xor(bq.z, off); bq.w += __shfl_xor(bq.w, off);
        }
        if (ng == 0) {
            float* bkt = bnpart + (blockIdx.x & 31) * 128;
            atomicAdd(&bkt[q * 4 + 0], bs.x);
            atomicAdd(&bkt[q * 4 + 1], bs.y);
            atomicAdd(&bkt[q * 4 + 2], bs.z);
            atomicAdd(&bkt[q * 4 + 3], bs.w);
            atomicAdd(&bkt[64 + q * 4 + 0], bq.x);
            atomicAdd(&bkt[64 + q * 4 + 1], bq.y);
            atomicAdd(&bkt[64 + q * 4 + 2], bq.z);
            atomicAdd(&bkt[64 + q * 4 + 3], bq.w);
        }
    }
}

__global__ void k_bnstat(const float* __restrict__ bnpart,
        const float* __restrict__ gamma, const float* __restrict__ beta,
        float* __restrict__ a, float* __restrict__ b, int N) {
    int c = threadIdx.x;  // 64 threads
    float s = 0.f, q = 0.f;
    for (int i = 0; i < 32; ++i) { s += bnpart[i * 128 + c]; q += bnpart[i * 128 + 64 + c]; }
    float invN = 1.0f / (float)N;
    float mu = s * invN;
    float var = q * invN - mu * mu;
    float ac = gamma[c] * rsqrtf(var + 1e-5f);
    a[c] = ac;
    b[c] = beta[c] - mu * ac;
}

// Head: z[g,320] = concat_l (a_l*S_l[g] + b_l*cnt[g]); out = relu(z@fc1+b)@fc2+b
__global__ __launch_bounds__(256) void k_final(
        const float* __restrict__ S, const float* __restrict__ ab,
        const int* __restrict__ cntg,
        const float* __restrict__ fc1W, const float* __restrict__ fc1b,
        const float* __restrict__ fc2W, const float* __restrict__ fc2b,
        float* __restrict__ out, int G) {
    __shared__ float zbuf[4][320];
    int tid = threadIdx.x;
    int lane = tid & 63, wv = tid >> 6;
    int g = blockIdx.x * 4 + wv;
    if (g >= G) return;
    float cf = (float)cntg[g];
#pragma unroll
    for (int l = 0; l < 5; ++l) {
        float a = ab[l * 128 + lane];
        float b = ab[l * 128 + 64 + lane];
        zbuf[wv][l * 64 + lane] = a * S[((size_t)l * G + g) * 64 + lane] + b * cf;
    }
    float acc = fc1b[lane];
    for (int k = 0; k < 320; ++k) acc += zbuf[wv][k] * fc1W[k * 64 + lane];
    float t = fmaxf(acc, 0.f);
    float r = t * fc2W[lane];
#pragma unroll
    for (int off = 32; off >= 1; off >>= 1) r += __shfl_xor(r, off);
    if (lane == 0) out[g] = r + fc2b[0];
}

extern "C" void kernel_launch(void* const* d_in, const int* in_sizes, int n_in,
                              void* d_out, int out_size, void* d_ws, size_t ws_size,
                              hipStream_t stream) {
    const float* x    = (const float*)d_in[0];
    const int*   ei   = (const int*)d_in[1];
    const int*   batch= (const int*)d_in[2];
    const float* W1a  = (const float*)d_in[3];
    const float* b1a  = (const float*)d_in[4];
    const float* W1b  = (const float*)d_in[5];
    const float* b1b  = (const float*)d_in[6];
    const float* Wa   = (const float*)d_in[7];
    const float* ba   = (const float*)d_in[8];
    const float* Wb   = (const float*)d_in[9];
    const float* bb   = (const float*)d_in[10];
    const float* gamma= (const float*)d_in[11];
    const float* beta = (const float*)d_in[12];
    const float* fc1W = (const float*)d_in[13];
    const float* fc1b = (const float*)d_in[14];
    const float* fc2W = (const float*)d_in[15];
    const float* fc2b = (const float*)d_in[16];

    const int N = in_sizes[2];
    const int E = in_sizes[1] / 2;
    const int G = out_size;
    const int* srcp = ei;
    const int* dstp = ei + E;

    char* p = (char*)d_ws;
    auto alloc = [&](size_t bytes) {
        char* r = p;
        p += (bytes + 255) & ~size_t(255);
        return r;
    };
    unsigned short* aggh = (unsigned short*)alloc((size_t)N * 64 * 2);
    unsigned short* vb   = (unsigned short*)alloc((size_t)N * 64 * 2);
    int*   col    = (int*)  alloc((size_t)E * 4);
    int*   rank_  = (int*)  alloc((size_t)E * 4);
    int*   rp     = (int*)  alloc((size_t)(N + 1) * 4);
    unsigned short* x16h = (unsigned short*)alloc((size_t)N * 16 * 2);
    float* h16    = (float*)alloc((size_t)N * 16 * 4);
    int*   bsum   = (int*)  alloc(512);
    int*   boffs  = (int*)  alloc(512);
    float* ab     = (float*)alloc(5 * 128 * 4);
    // ---- zeroed region (single memset) ----
    char*  z0     = p;
    int*   cntn   = (int*)  alloc((size_t)N * 4);
    int*   cntg   = (int*)  alloc((size_t)G * 4);
    float* S      = (float*)alloc((size_t)5 * G * 64 * 4);
    float* bnpart = (float*)alloc((size_t)5 * 32 * 128 * 4);
    size_t zbytes = (size_t)(p - z0);

    hipMemsetAsync(z0, 0, zbytes, stream);

    int nb_e = (E + 255) / 256;
    int nb_n = (N + 255) / 256;
    int nb_scan = (N + SCAN_ELEMS - 1) / SCAN_ELEMS;
    k_hist<<<nb_e, 256, 0, stream>>>(dstp, E, cntn, rank_);
    k_prep<<<nb_n, 256, 0, stream>>>(x, x16h, batch, cntg, N);
    k_scan1<<<nb_scan, 256, 0, stream>>>(cntn, N, rp, bsum);
    k_scan2<<<1, 128, 0, stream>>>(bsum, nb_scan, boffs);
    k_scan3<<<(N + 255) / 256, 256, 0, stream>>>(rp, N, boffs, E);
    k_fill<<<nb_e, 256, 0, stream>>>(srcp, dstp, rank_, E, rp, col);

    int nb_node = (N + 3) / 4;
    int nb_tile = (N + 63) / 64;

    // Layer 1: 16-dim fp16 gather, then mlp<FIRST> does W1a from h16 (fp32)
    k_gather16<<<nb_node, 256, 0, stream>>>(x16h, h16, rp, col, N);
    k_mlp<true><<<nb_tile, 256, 0, stream>>>(h16, vb, batch,
        W1a, b1a, W1b, b1b, S, bnpart, N);
    k_bnstat<<<1, 64, 0, stream>>>(bnpart, gamma, beta, ab, ab + 64, N);

    for (int l = 0; l < 4; ++l) {
        k_gather<<<nb_node, 256, 0, stream>>>(vb, aggh, rp, col,
            ab + l * 128, N);
        k_mlp<false><<<nb_tile, 256, 0, stream>>>(aggh, vb, batch,
            Wa + l * 4096, ba + l * 64, Wb + l * 4096, bb + l * 64,
            S + (size_t)(l + 1) * G * 64,
            bnpart + (size_t)(l + 1) * 32 * 128, N);
        k_bnstat<<<1, 64, 0, stream>>>(
            bnpart + (size_t)(l + 1) * 32 * 128,
            gamma + (l + 1) * 64, beta + (l + 1) * 64,
            ab + (l + 1) * 128, ab + (l + 1) * 128 + 64, N);
    }

    k_final<<<(G + 3) / 4, 256, 0, stream>>>(S, ab, cntg, fc1W, fc1b, fc2W, fc2b,
                                             (float*)d_out, G);
}